// Round 14
// baseline (128.479 us; speedup 1.0000x reference)
//
#include <hip/hip_runtime.h>
#include <hip/hip_bf16.h>
#include <math.h>

#define BATCHN  16
#define SEQ     1024
#define DMODEL  256
#define DSTATE  128
#define HEADDIM 64
#define DINNER  512
#define NHEADS  8
#define CONVDIM 768
#define DINPROJ 1288
#define ZXLD    1280
#define KCONV   4
#define NCHUNK  16
#define LCHUNK  64
#define EPSV    1e-5f
#define ROWS    (BATCHN*SEQ)

typedef __attribute__((ext_vector_type(8))) __bf16 bf16x8;
typedef __attribute__((ext_vector_type(4))) float  f32x4;

__device__ inline ushort f2bf(float f) {
    union { float f; uint32_t u; } v; v.f = f;
    uint32_t r = v.u + 0x7fff + ((v.u >> 16) & 1);
    return (ushort)(r >> 16);
}
__device__ inline float bf2f(ushort u) {
    union { uint32_t u; float f; } v; v.u = ((uint32_t)u) << 16;
    return v.f;
}

// ---------- prep: dt GEMV + u->bf16 cast (blocks 0..511) | W transposes (512..959)
__global__ __launch_bounds__(256) void prep_k(const float* __restrict__ u,
                                              const float* __restrict__ W_in,
                                              const float* __restrict__ W_out,
                                              const float* __restrict__ dt_bias,
                                              const float* __restrict__ A_log,
                                              ushort* __restrict__ ubf,
                                              float* __restrict__ dtb,
                                              float* __restrict__ adtb,
                                              ushort* __restrict__ WtA,
                                              ushort* __restrict__ WtB) {
    __shared__ union {
        struct { float Uld[32][264]; float Ws[DMODEL][NHEADS]; } d;
        float Ts[32][33];
    } S;
    const int tid = threadIdx.x;
    if (blockIdx.x < 512) {
        #pragma unroll
        for (int j = 0; j < 8; ++j) {
            int idx = tid + j * 256;
            S.d.Ws[idx >> 3][idx & 7] = W_in[(size_t)(idx >> 3) * DINPROJ + 1280 + (idx & 7)];
        }
        const int row0 = blockIdx.x * 32;
        #pragma unroll
        for (int v = 0; v < 8; ++v) {
            int e = v * 1024 + tid * 4;
            int r = e >> 8, cc = e & 255;
            float4 x = *(const float4*)&u[(size_t)(row0 + r) * DMODEL + cc];
            *(float4*)&S.d.Uld[r][cc] = x;
            ushort t4[4];
            t4[0]=f2bf(x.x); t4[1]=f2bf(x.y); t4[2]=f2bf(x.z); t4[3]=f2bf(x.w);
            *(ushort4*)&ubf[(size_t)(row0 + r) * DMODEL + cc] = *(ushort4*)t4;
        }
        __syncthreads();
        const int row = tid >> 3, h = tid & 7;
        float acc = 0.f;
        #pragma unroll 8
        for (int k = 0; k < DMODEL; k += 4) {
            float4 uv = *(const float4*)&S.d.Uld[row][k];
            acc += uv.x * S.d.Ws[k][h] + uv.y * S.d.Ws[k+1][h]
                 + uv.z * S.d.Ws[k+2][h] + uv.w * S.d.Ws[k+3][h];
        }
        float v = acc + dt_bias[h];
        float dt = (v > 20.f) ? v : log1pf(__expf(v));
        dtb [(size_t)(row0 + row) * NHEADS + h] = dt;
        adtb[(size_t)(row0 + row) * NHEADS + h] = dt * (-__expf(A_log[h]));
    } else {
        int bid = blockIdx.x - 512;
        const float* src; ushort* dst; int K, ldsrc, nx;
        if (bid < 320) { src = W_in;  dst = WtA; K = DMODEL; ldsrc = DINPROJ; nx = 40; }
        else { bid -= 320; src = W_out; dst = WtB; K = DINNER; ldsrc = DMODEL; nx = 8; }
        const int n0 = (bid % nx) * 32, k0 = (bid / nx) * 32;
        const int tx = tid & 31, ty = tid >> 5;
        #pragma unroll
        for (int j = 0; j < 4; ++j) {
            int kl = ty * 4 + j;
            S.Ts[kl][tx] = src[(size_t)(k0 + kl) * ldsrc + n0 + tx];
        }
        __syncthreads();
        #pragma unroll
        for (int j = 0; j < 4; ++j) {
            int nl = ty * 4 + j;
            dst[(size_t)(n0 + nl) * K + k0 + tx] = f2bf(S.Ts[tx][nl]);
        }
    }
}

// ------------------------------------------------------- bf16 MFMA GEMM
#define LDSW 72
#define TILEC 132
template<typename CT>
__global__ __launch_bounds__(256) void gemm_bf16(const ushort* __restrict__ A,
                                                 const ushort* __restrict__ Bt,
                                                 CT* __restrict__ C,
                                                 int M, int N, int K, int nx) {
    __shared__ ushort LB[2 * 128 * LDSW];
    ushort* As = LB;
    ushort* Bs = LB + 128 * LDSW;
    const int tid  = threadIdx.x;
    const int nwg  = gridDim.x;
    const int work = (blockIdx.x & 7) * (nwg >> 3) + (blockIdx.x >> 3);
    const int m0 = (work / nx) * 128, n0 = (work % nx) * 128;
    const int wid = tid >> 6, lane = tid & 63;
    const int wr = wid >> 1, wc = wid & 1;
    const int r = tid >> 1, kq = tid & 1;
    const int fr = lane & 15, kc = lane >> 4;

    f32x4 acc[4][4];
    #pragma unroll
    for (int i = 0; i < 4; ++i)
        #pragma unroll
        for (int j = 0; j < 4; ++j) acc[i][j] = (f32x4)0.f;

    for (int kt = 0; kt < K; kt += 64) {
        const ushort* ap = &A [(size_t)(m0 + r) * K + kt + kq * 32];
        const ushort* bp = &Bt[(size_t)(n0 + r) * K + kt + kq * 32];
        #pragma unroll
        for (int v = 0; v < 4; ++v) {
            *(uint4*)&As[r * LDSW + kq * 32 + v * 8] = *(const uint4*)(ap + v * 8);
            *(uint4*)&Bs[r * LDSW + kq * 32 + v * 8] = *(const uint4*)(bp + v * 8);
        }
        __syncthreads();
        #pragma unroll
        for (int kk = 0; kk < 2; ++kk) {
            bf16x8 af[4], bfv[4];
            #pragma unroll
            for (int i = 0; i < 4; ++i) {
                af[i]  = *(const bf16x8*)&As[(wr * 64 + i * 16 + fr) * LDSW + kk * 32 + kc * 8];
                bfv[i] = *(const bf16x8*)&Bs[(wc * 64 + i * 16 + fr) * LDSW + kk * 32 + kc * 8];
            }
            #pragma unroll
            for (int i = 0; i < 4; ++i)
                #pragma unroll
                for (int j = 0; j < 4; ++j)
                    acc[i][j] = __builtin_amdgcn_mfma_f32_16x16x32_bf16(af[i], bfv[j], acc[i][j], 0, 0, 0);
        }
        __syncthreads();
    }
    if constexpr (sizeof(CT) == 4) {
        #pragma unroll
        for (int i = 0; i < 4; ++i)
            #pragma unroll
            for (int j = 0; j < 4; ++j)
                #pragma unroll
                for (int q = 0; q < 4; ++q) {
                    int rr = m0 + wr * 64 + i * 16 + (lane >> 4) * 4 + q;
                    int cc = n0 + wc * 64 + j * 16 + (lane & 15);
                    C[(size_t)rr * N + cc] = acc[i][j][q];
                }
    } else {
        ushort (*Tile)[TILEC] = (ushort (*)[TILEC])LB;
        #pragma unroll
        for (int i = 0; i < 4; ++i)
            #pragma unroll
            for (int j = 0; j < 4; ++j)
                #pragma unroll
                for (int q = 0; q < 4; ++q)
                    Tile[wr * 64 + i * 16 + (lane >> 4) * 4 + q]
                        [wc * 64 + j * 16 + (lane & 15)] = f2bf(acc[i][j][q]);
        __syncthreads();
        #pragma unroll
        for (int it = 0; it < 8; ++it) {
            int idx = tid + it * 256;
            int rr = idx >> 4, g = idx & 15;
            *(uint4*)&C[(size_t)(m0 + rr) * N + n0 + g * 8] = *(uint4*)&Tile[rr][g * 8];
        }
    }
}

// ------------------- depthwise conv + SiLU: LDS weights, 4 t-steps/thread
__global__ __launch_bounds__(256) void conv_silu_k(const ushort* __restrict__ zx,
                                                   const float* __restrict__ cw,
                                                   const float* __restrict__ cb,
                                                   ushort* __restrict__ out) {
    __shared__ float cws[KCONV][CONVDIM];
    __shared__ float cbs[CONVDIM];
    const int tid = threadIdx.x;
    #pragma unroll
    for (int it = 0; it < 3; ++it) {
        int i = tid + it * 256;
        cbs[i] = cb[i];
        #pragma unroll
        for (int k = 0; k < KCONV; ++k) cws[k][i] = cw[i * KCONV + k];
    }
    __syncthreads();

    const int idx = blockIdx.x * 256 + tid;
    const int cg = idx % 96, btq = idx / 96;
    const int c0 = cg * 8;
    const int bt0 = btq * 4;
    const int t0 = bt0 & (SEQ - 1);

    float wv[KCONV][8], bias[8];
    #pragma unroll
    for (int j = 0; j < 8; ++j) bias[j] = cbs[c0 + j];
    #pragma unroll
    for (int k = 0; k < KCONV; ++k) {
        float4 a = *(const float4*)&cws[k][c0];
        float4 b = *(const float4*)&cws[k][c0 + 4];
        wv[k][0] = a.x; wv[k][1] = a.y; wv[k][2] = a.z; wv[k][3] = a.w;
        wv[k][4] = b.x; wv[k][5] = b.y; wv[k][6] = b.z; wv[k][7] = b.w;
    }
    float xr[7][8];
    #pragma unroll
    for (int r = 0; r < 7; ++r) {
        int tt = t0 - 3 + r;
        if (tt >= 0) {
            uint4 v = *(const uint4*)&zx[(size_t)(bt0 - 3 + r) * ZXLD + DINNER + c0];
            const ushort* pv = (const ushort*)&v;
            #pragma unroll
            for (int j = 0; j < 8; ++j) xr[r][j] = bf2f(pv[j]);
        } else {
            #pragma unroll
            for (int j = 0; j < 8; ++j) xr[r][j] = 0.f;
        }
    }
    #pragma unroll
    for (int dt = 0; dt < 4; ++dt) {
        float acc[8];
        #pragma unroll
        for (int j = 0; j < 8; ++j) acc[j] = bias[j];
        #pragma unroll
        for (int k = 0; k < KCONV; ++k)
            #pragma unroll
            for (int j = 0; j < 8; ++j) acc[j] += xr[dt + k][j] * wv[k][j];
        ushort res[8];
        #pragma unroll
        for (int j = 0; j < 8; ++j)
            res[j] = f2bf(acc[j] / (1.f + __expf(-acc[j])));
        *(uint4*)&out[(size_t)(bt0 + dt) * CONVDIM + c0] = *(uint4*)res;
    }
}

// -------------------- states-only SSD kernel (cumsum + S = Xd^T B)
#define SLDB 72
__global__ __launch_bounds__(256) void states_k(const ushort* __restrict__ xbc,
                                                const float* __restrict__ dtb,
                                                const float* __restrict__ adtb,
                                                ushort* __restrict__ states,
                                                float* __restrict__ acsbuf,
                                                float* __restrict__ chunksum) {
    const int wk = (blockIdx.x & 7) * 64 + (blockIdx.x >> 3);
    const int hgrp = wk & 1, c = (wk >> 1) & 15, b = wk >> 5;
    const int row0 = b * SEQ + c * LCHUNK;
    const int tid = threadIdx.x;
    const int lane = tid & 63, w = tid >> 6;
    const int fr = lane & 15, kc = lane >> 4;

    __shared__ ushort Btr[128][SLDB];
    __shared__ ushort Xdt[64][SLDB];
    __shared__ float dts[4][64];
    __shared__ float decs[4][64];

    {
        const int hh = hgrp * 4 + w;
        float v = adtb[(size_t)(row0 + lane) * NHEADS + hh];
        #pragma unroll
        for (int off = 1; off < 64; off <<= 1) {
            float t = __shfl_up(v, off);
            if (lane >= off) v += t;
        }
        float tot = __shfl(v, 63);
        decs[w][lane] = __expf(tot - v);
        acsbuf[(((size_t)b * NCHUNK + c) * NHEADS + hh) * LCHUNK + lane] = v;
        if (lane == 63) chunksum[((size_t)b * NCHUNK + c) * NHEADS + hh] = v;
        dts[w][lane] = dtb[(size_t)(row0 + lane) * NHEADS + hh];
    }
    for (int it = 0; it < 4; ++it) {
        int idx = tid + it * 256;
        int l = idx >> 4, ng = idx & 15;
        uint4 vb = *(const uint4*)&xbc[(size_t)(row0 + l) * CONVDIM + DINNER + ng * 8];
        const ushort* pv = (const ushort*)&vb;
        #pragma unroll
        for (int j = 0; j < 8; ++j) Btr[ng * 8 + j][l] = pv[j];
    }
    __syncthreads();

    for (int hl = 0; hl < 4; ++hl) {
        const int hh = hgrp * 4 + hl;
        {
            const int p = lane;
            ushort xdt[16];
            #pragma unroll
            for (int j = 0; j < 16; ++j) {
                int l = w * 16 + j;
                float xv = bf2f(xbc[(size_t)(row0 + l) * CONVDIM + hh * HEADDIM + p])
                           * dts[hl][l];
                xdt[j] = f2bf(xv * decs[hl][l]);
            }
            #pragma unroll
            for (int v = 0; v < 4; ++v)
                *(ushort4*)&Xdt[p][w*16 + v*4] = *(ushort4*)&xdt[v*4];
        }
        __syncthreads();
        {
            f32x4 acc2[4][2];
            #pragma unroll
            for (int mt = 0; mt < 4; ++mt)
                #pragma unroll
                for (int jt = 0; jt < 2; ++jt) acc2[mt][jt] = (f32x4)0.f;
            #pragma unroll
            for (int kt = 0; kt < 2; ++kt) {
                bf16x8 a4[4], b2[2];
                #pragma unroll
                for (int mt = 0; mt < 4; ++mt) a4[mt] = *(const bf16x8*)&Xdt[mt*16 + fr][kt*32 + kc*8];
                #pragma unroll
                for (int jt = 0; jt < 2; ++jt) b2[jt] = *(const bf16x8*)&Btr[w*32 + jt*16 + fr][kt*32 + kc*8];
                #pragma unroll
                for (int mt = 0; mt < 4; ++mt)
                    #pragma unroll
                    for (int jt = 0; jt < 2; ++jt)
                        acc2[mt][jt] = __builtin_amdgcn_mfma_f32_16x16x32_bf16(a4[mt], b2[jt], acc2[mt][jt], 0, 0, 0);
            }
            ushort* sb = states + ((((size_t)b * NCHUNK + c) * NHEADS + hh) * HEADDIM) * DSTATE;
            #pragma unroll
            for (int mt = 0; mt < 4; ++mt)
                #pragma unroll
                for (int jt = 0; jt < 2; ++jt)
                    #pragma unroll
                    for (int q = 0; q < 4; ++q) {
                        int p = mt*16 + (lane >> 4)*4 + q;
                        int n = w*32 + jt*16 + fr;
                        sb[(size_t)p * DSTATE + n] = f2bf(acc2[mt][jt][q]);
                    }
        }
        __syncthreads();
    }
}

// ------------------------------------- inter-chunk scan (bf16 states, f32 regs)
__global__ __launch_bounds__(256) void scan_k(ushort* __restrict__ states,
                                              const float* __restrict__ chunksum) {
    const int bid = blockIdx.x;
    const int pq = bid & 3, h = (bid >> 2) & 7, b = bid >> 5;
    const int tid = threadIdx.x;
    float pref[8];
    #pragma unroll
    for (int k = 0; k < 8; ++k) pref[k] = 0.f;
    for (int c = 0; c < NCHUNK; ++c) {
        ushort* base = states + (((size_t)b * NCHUNK + c) * NHEADS + h) * (HEADDIM * DSTATE)
                       + pq * 2048 + tid * 8;
        float dec = __expf(chunksum[((size_t)b * NCHUNK + c) * NHEADS + h]);
        uint4 v = *(const uint4*)base;
        const ushort* pv = (const ushort*)&v;
        ushort outv[8];
        #pragma unroll
        for (int j = 0; j < 8; ++j) {
            float cur = bf2f(pv[j]);
            outv[j] = f2bf(pref[j]);
            pref[j] = dec * pref[j] + cur;
        }
        *(uint4*)base = *(uint4*)outv;
    }
}

// ----- tail: Y_diag (G,P,PX) + Y_off (C.S^T) + gate + RMSNorm -> bf16 g
// 512 blocks (32-row halves, XCD-chunked), 256 thr, ~74 KB LDS -> 2/CU
#define SLDA 136
__global__ __launch_bounds__(256) void tail_k(const ushort* __restrict__ xbc,
                                              const ushort* __restrict__ states,
                                              const float* __restrict__ acsbuf,
                                              const float* __restrict__ dtb,
                                              const float* __restrict__ Dp,
                                              const ushort* __restrict__ zx,
                                              const float* __restrict__ nw,
                                              ushort* __restrict__ gbuf) {
    const int wk = (blockIdx.x & 7) * 64 + (blockIdx.x >> 3);
    const int half = wk & 1, c = (wk >> 1) & 15, b = wk >> 5;
    const int rowC0 = b * SEQ + c * LCHUNK;          // chunk base
    const int row0  = rowC0 + half * 32;             // this block's rows
    const int tid = threadIdx.x;
    const int lane = tid & 63, w = tid >> 6;
    const int fr = lane & 15, kc = lane >> 4;
    const int ri = w & 1;                            // row-frag (of 2)
    const int cj0 = (w >> 1) * 2;                    // col-frag pair base (of 4)

    __shared__ union {
        ushort Bs [64][SLDA];    // G phase
        ushort Ssh[64][SLDA];    // per-head S prefix
    } U;
    __shared__ ushort Csh[32][SLDA];
    __shared__ ushort Ps [32][SLDB];
    __shared__ ushort Xt [64][SLDB];
    __shared__ ushort Ys [32][520];
    __shared__ float acs_s[64], dts_s[64], ea[32];

    // stage C (this half's 32 rows) and B (full 64 rows)
    #pragma unroll
    for (int it = 0; it < 2; ++it) {
        int idx = tid + it * 256;
        int l = idx >> 4, ng = idx & 15;
        *(uint4*)&Csh[l][ng * 8] =
            *(const uint4*)&xbc[(size_t)(row0 + l) * CONVDIM + DINNER + DSTATE + ng * 8];
    }
    #pragma unroll
    for (int it = 0; it < 4; ++it) {
        int idx = tid + it * 256;
        int l = idx >> 4, ng = idx & 15;
        *(uint4*)&U.Bs[l][ng * 8] =
            *(const uint4*)&xbc[(size_t)(rowC0 + l) * CONVDIM + DINNER + ng * 8];
    }
    __syncthreads();

    // G = C . B^T  (32 x 64), wave w -> row-frag ri, col-frags cj0,cj0+1
    f32x4 accG[2];
    accG[0] = (f32x4)0.f; accG[1] = (f32x4)0.f;
    #pragma unroll
    for (int kt = 0; kt < 4; ++kt) {
        bf16x8 af = *(const bf16x8*)&Csh[ri*16 + fr][kt*32 + kc*8];
        #pragma unroll
        for (int jj = 0; jj < 2; ++jj) {
            bf16x8 bfv = *(const bf16x8*)&U.Bs[(cj0+jj)*16 + fr][kt*32 + kc*8];
            accG[jj] = __builtin_amdgcn_mfma_f32_16x16x32_bf16(af, bfv, accG[jj], 0, 0, 0);
        }
    }

    for (int hl = 0; hl < NHEADS; ++hl) {
        __syncthreads();    // G's Bs reads done (hl=0) / prev head MFMAs done
        // stage S prefix for head hl (overlays Bs)
        const ushort* sb = states + ((((size_t)b * NCHUNK + c) * NHEADS + hl) * HEADDIM) * DSTATE;
        #pragma unroll
        for (int it = 0; it < 4; ++it) {
            int idx = tid + it * 256;
            int p = idx >> 4, ng = idx & 15;
            *(uint4*)&U.Ssh[p][ng * 8] = *(const uint4*)&sb[(size_t)p * DSTATE + ng * 8];
        }
        if (tid < 64) {
            acs_s[tid] = acsbuf[(((size_t)b * NCHUNK + c) * NHEADS + hl) * LCHUNK + tid];
            dts_s[tid] = dtb[(size_t)(rowC0 + tid) * NHEADS + hl];
        }
        __syncthreads();    // acs/dts ready
        // build Xt (full 64 p-rows x 64 l-cols): thread covers 16 elems
        {
            int l = tid >> 2, pg = tid & 3;
            float dt_l = dts_s[l];
            #pragma unroll
            for (int h2 = 0; h2 < 2; ++h2) {
                uint4 xv4 = *(const uint4*)&xbc[(size_t)(rowC0 + l) * CONVDIM
                                                + hl * HEADDIM + h2 * 32 + pg * 8];
                const ushort* pv = (const ushort*)&xv4;
                #pragma unroll
                for (int j = 0; j < 8; ++j)
                    Xt[h2*32 + pg*8 + j][l] = f2bf(bf2f(pv[j]) * dt_l);
            }
        }
        // build P (rows: this half's 32; cols: full 64)
        const float Dh = Dp[hl];
        #pragma unroll
        for (int jj = 0; jj < 2; ++jj)
            #pragma unroll
            for (int q = 0; q < 4; ++q) {
                int ll = ri*16 + (lane >> 4)*4 + q;      // local row
                int lg = half*32 + ll;                   // global row in chunk
                int s  = (cj0+jj)*16 + fr;
                float v = 0.f;
                if (s < lg)       v = accG[jj][q] * __expf(acs_s[lg] - acs_s[s]);
                else if (s == lg) v = accG[jj][q] + Dh / dts_s[lg];
                Ps[ll][s] = f2bf(v);
            }
        if (tid < 32) ea[tid] = __expf(acs_s[half*32 + tid]);
        __syncthreads();    // Ps/Xt/Ssh/ea ready
        // accD = P @ Xt^T (K=64), accO = C @ S^T (K=128); wave -> (ri, cj0+jj)
        f32x4 accD[2], accO[2];
        accD[0] = (f32x4)0.f; accD[1] = (f32x4)0.f;
        accO[0] = (f32x4)0.f; accO[1] = (f32x4)0.f;
        #pragma unroll
        for (int kt = 0; kt < 2; ++kt) {
            bf16x8 af = *(const bf16x8*)&Ps[ri*16 + fr][kt*32 + kc*8];
            #pragma unroll
            for (int jj = 0; jj < 2; ++jj) {
                bf16x8 bfv = *(const bf16x8*)&Xt[(cj0+jj)*16 + fr][kt*32 + kc*8];
                accD[jj] = __builtin_amdgcn_mfma_f32_16x16x32_bf16(af, bfv, accD[jj], 0, 0, 0);
            }
        }
        #pragma unroll
        for (int kt = 0; kt < 4; ++kt) {
            bf16x8 af = *(const bf16x8*)&Csh[ri*16 + fr][kt*32 + kc*8];
            #pragma unroll
            for (int jj = 0; jj < 2; ++jj) {
                bf16x8 bfv = *(const bf16x8*)&U.Ssh[(cj0+jj)*16 + fr][kt*32 + kc*8];
                accO[jj] = __builtin_amdgcn_mfma_f32_16x16x32_bf16(af, bfv, accO[jj], 0, 0, 0);
            }
        }
        #pragma unroll
        for (int jj = 0; jj < 2; ++jj)
            #pragma unroll
            for (int q = 0; q < 4; ++q) {
                int ll = ri*16 + (lane >> 4)*4 + q;
                int p  = (cj0+jj)*16 + fr;
                Ys[ll][hl * HEADDIM + p] = f2bf(accD[jj][q] + accO[jj][q] * ea[ll]);
            }
    }
    __syncthreads();
    // gate + RMSNorm: wave w -> rows w*8 .. w*8+7
    float nwv[8];
    #pragma unroll
    for (int j = 0; j < 8; ++j) nwv[j] = nw[lane * 8 + j];
    #pragma unroll
    for (int i = 0; i < 8; ++i) {
        int l = w * 8 + i;
        int row = row0 + l;
        uint4 zv = *(const uint4*)&zx[(size_t)row * ZXLD + lane * 8];
        const ushort* pz = (const ushort*)&zv;
        float g[8], ss = 0.f;
        #pragma unroll
        for (int j = 0; j < 8; ++j) {
            float y = bf2f(Ys[l][lane * 8 + j]);
            float z = bf2f(pz[j]);
            float sz = z / (1.f + __expf(-z));
            g[j] = y * sz;
            ss += g[j] * g[j];
        }
        #pragma unroll
        for (int off = 32; off; off >>= 1) ss += __shfl_xor(ss, off);
        float r = rsqrtf(ss / (float)DINNER + EPSV);
        ushort res[8];
        #pragma unroll
        for (int j = 0; j < 8; ++j) res[j] = f2bf(g[j] * r * nwv[j]);
        *(uint4*)&gbuf[(size_t)row * DINNER + lane * 8] = *(uint4*)res;
    }
}

// ---------------------------------------------------------------- launch
extern "C" void kernel_launch(void* const* d_in, const int* in_sizes, int n_in,
                              void* d_out, int out_size, void* d_ws, size_t ws_size,
                              hipStream_t stream) {
    const float* u       = (const float*)d_in[0];
    const float* W_in    = (const float*)d_in[1];
    const float* conv_w  = (const float*)d_in[2];
    const float* conv_b  = (const float*)d_in[3];
    const float* dt_bias = (const float*)d_in[4];
    const float* A_log   = (const float*)d_in[5];
    const float* Dp      = (const float*)d_in[6];
    const float* norm_w  = (const float*)d_in[7];
    const float* W_out   = (const float*)d_in[8];
    float* out = (float*)d_out;

    char* p = (char*)d_ws;
    ushort* zx       = (ushort*)p; p += (size_t)ROWS * ZXLD * sizeof(ushort);
    ushort* gbuf     = (ushort*)p; p += (size_t)ROWS * DINNER * sizeof(ushort);
    ushort* states   = (ushort*)p; p += (size_t)BATCHN * NCHUNK * NHEADS * HEADDIM * DSTATE * sizeof(ushort);
    ushort* xbc      = (ushort*)p; p += (size_t)ROWS * CONVDIM * sizeof(ushort);
    ushort* ubf      = (ushort*)p; p += (size_t)ROWS * DMODEL * sizeof(ushort);
    float*  dtb      = (float*)p;  p += (size_t)ROWS * NHEADS  * sizeof(float);
    float*  adtb     = (float*)p;  p += (size_t)ROWS * NHEADS  * sizeof(float);
    float*  chunksum = (float*)p;  p += (size_t)BATCHN * NCHUNK * NHEADS * sizeof(float);
    float*  acsbuf   = (float*)p;  p += (size_t)BATCHN * NCHUNK * NHEADS * LCHUNK * sizeof(float);
    ushort* WtA      = (ushort*)p; p += (size_t)ZXLD * DMODEL * sizeof(ushort);
    ushort* WtB      = (ushort*)p; p += (size_t)DMODEL * DINNER * sizeof(ushort);

    prep_k<<<960, 256, 0, stream>>>(u, W_in, W_out, dt_bias, A_log,
                                    ubf, dtb, adtb, WtA, WtB);
    gemm_bf16<ushort><<<(ZXLD/128)*(ROWS/128), 256, 0, stream>>>(
        ubf, WtA, zx, ROWS, ZXLD, DMODEL, ZXLD/128);
    conv_silu_k<<<(ROWS/4)*96/256, 256, 0, stream>>>(zx, conv_w, conv_b, xbc);
    states_k<<<512, 256, 0, stream>>>(xbc, dtb, adtb, states, acsbuf, chunksum);
    scan_k<<<BATCHN*NHEADS*4, 256, 0, stream>>>(states, chunksum);
    tail_k<<<512, 256, 0, stream>>>(xbc, states, acsbuf, dtb, Dp, zx, norm_w, gbuf);
    gemm_bf16<float><<<(DMODEL/128)*(ROWS/128), 256, 0, stream>>>(
        gbuf, WtB, out, ROWS, DMODEL, DINNER, DMODEL/128);
}

// Round 15
// 125.293 us; speedup vs baseline: 1.0254x; 1.0254x over previous
//
#include <hip/hip_runtime.h>
#include <hip/hip_bf16.h>
#include <math.h>

#define BATCHN  16
#define SEQ     1024
#define DMODEL  256
#define DSTATE  128
#define HEADDIM 64
#define DINNER  512
#define NHEADS  8
#define CONVDIM 768
#define DINPROJ 1288
#define ZXLD    1280
#define KCONV   4
#define NCHUNK  16
#define LCHUNK  64
#define EPSV    1e-5f
#define ROWS    (BATCHN*SEQ)

typedef __attribute__((ext_vector_type(8))) __bf16 bf16x8;
typedef __attribute__((ext_vector_type(4))) float  f32x4;

__device__ inline ushort f2bf(float f) {
    union { float f; uint32_t u; } v; v.f = f;
    uint32_t r = v.u + 0x7fff + ((v.u >> 16) & 1);
    return (ushort)(r >> 16);
}
__device__ inline float bf2f(ushort u) {
    union { uint32_t u; float f; } v; v.u = ((uint32_t)u) << 16;
    return v.f;
}

// ---------- prep: dt GEMV + u->bf16 cast (blocks 0..511) | W transposes (512..959)
__global__ __launch_bounds__(256) void prep_k(const float* __restrict__ u,
                                              const float* __restrict__ W_in,
                                              const float* __restrict__ W_out,
                                              const float* __restrict__ dt_bias,
                                              const float* __restrict__ A_log,
                                              ushort* __restrict__ ubf,
                                              float* __restrict__ dtb,
                                              float* __restrict__ adtb,
                                              ushort* __restrict__ WtA,
                                              ushort* __restrict__ WtB) {
    __shared__ union {
        struct { float Uld[32][264]; float Ws[DMODEL][NHEADS]; } d;
        float Ts[32][33];
    } S;
    const int tid = threadIdx.x;
    if (blockIdx.x < 512) {
        #pragma unroll
        for (int j = 0; j < 8; ++j) {
            int idx = tid + j * 256;
            S.d.Ws[idx >> 3][idx & 7] = W_in[(size_t)(idx >> 3) * DINPROJ + 1280 + (idx & 7)];
        }
        const int row0 = blockIdx.x * 32;
        #pragma unroll
        for (int v = 0; v < 8; ++v) {
            int e = v * 1024 + tid * 4;
            int r = e >> 8, cc = e & 255;
            float4 x = *(const float4*)&u[(size_t)(row0 + r) * DMODEL + cc];
            *(float4*)&S.d.Uld[r][cc] = x;
            ushort t4[4];
            t4[0]=f2bf(x.x); t4[1]=f2bf(x.y); t4[2]=f2bf(x.z); t4[3]=f2bf(x.w);
            *(ushort4*)&ubf[(size_t)(row0 + r) * DMODEL + cc] = *(ushort4*)t4;
        }
        __syncthreads();
        const int row = tid >> 3, h = tid & 7;
        float acc = 0.f;
        #pragma unroll 8
        for (int k = 0; k < DMODEL; k += 4) {
            float4 uv = *(const float4*)&S.d.Uld[row][k];
            acc += uv.x * S.d.Ws[k][h] + uv.y * S.d.Ws[k+1][h]
                 + uv.z * S.d.Ws[k+2][h] + uv.w * S.d.Ws[k+3][h];
        }
        float v = acc + dt_bias[h];
        float dt = (v > 20.f) ? v : log1pf(__expf(v));
        dtb [(size_t)(row0 + row) * NHEADS + h] = dt;
        adtb[(size_t)(row0 + row) * NHEADS + h] = dt * (-__expf(A_log[h]));
    } else {
        int bid = blockIdx.x - 512;
        const float* src; ushort* dst; int K, ldsrc, nx;
        if (bid < 320) { src = W_in;  dst = WtA; K = DMODEL; ldsrc = DINPROJ; nx = 40; }
        else { bid -= 320; src = W_out; dst = WtB; K = DINNER; ldsrc = DMODEL; nx = 8; }
        const int n0 = (bid % nx) * 32, k0 = (bid / nx) * 32;
        const int tx = tid & 31, ty = tid >> 5;
        #pragma unroll
        for (int j = 0; j < 4; ++j) {
            int kl = ty * 4 + j;
            S.Ts[kl][tx] = src[(size_t)(k0 + kl) * ldsrc + n0 + tx];
        }
        __syncthreads();
        #pragma unroll
        for (int j = 0; j < 4; ++j) {
            int nl = ty * 4 + j;
            dst[(size_t)(n0 + nl) * K + k0 + tx] = f2bf(S.Ts[tx][nl]);
        }
    }
}

// ------------------------------------------------------- bf16 MFMA GEMM
// bf16 output path repacks the tile through LDS -> uint4 stores.
#define LDSW 72
#define TILEC 132
template<typename CT>
__global__ __launch_bounds__(256) void gemm_bf16(const ushort* __restrict__ A,
                                                 const ushort* __restrict__ Bt,
                                                 CT* __restrict__ C,
                                                 int M, int N, int K, int nx) {
    __shared__ ushort LB[2 * 128 * LDSW];
    ushort* As = LB;
    ushort* Bs = LB + 128 * LDSW;
    const int tid  = threadIdx.x;
    const int nwg  = gridDim.x;
    const int work = (blockIdx.x & 7) * (nwg >> 3) + (blockIdx.x >> 3);
    const int m0 = (work / nx) * 128, n0 = (work % nx) * 128;
    const int wid = tid >> 6, lane = tid & 63;
    const int wr = wid >> 1, wc = wid & 1;
    const int r = tid >> 1, kq = tid & 1;
    const int fr = lane & 15, kc = lane >> 4;

    f32x4 acc[4][4];
    #pragma unroll
    for (int i = 0; i < 4; ++i)
        #pragma unroll
        for (int j = 0; j < 4; ++j) acc[i][j] = (f32x4)0.f;

    for (int kt = 0; kt < K; kt += 64) {
        const ushort* ap = &A [(size_t)(m0 + r) * K + kt + kq * 32];
        const ushort* bp = &Bt[(size_t)(n0 + r) * K + kt + kq * 32];
        #pragma unroll
        for (int v = 0; v < 4; ++v) {
            *(uint4*)&As[r * LDSW + kq * 32 + v * 8] = *(const uint4*)(ap + v * 8);
            *(uint4*)&Bs[r * LDSW + kq * 32 + v * 8] = *(const uint4*)(bp + v * 8);
        }
        __syncthreads();
        #pragma unroll
        for (int kk = 0; kk < 2; ++kk) {
            bf16x8 af[4], bfv[4];
            #pragma unroll
            for (int i = 0; i < 4; ++i) {
                af[i]  = *(const bf16x8*)&As[(wr * 64 + i * 16 + fr) * LDSW + kk * 32 + kc * 8];
                bfv[i] = *(const bf16x8*)&Bs[(wc * 64 + i * 16 + fr) * LDSW + kk * 32 + kc * 8];
            }
            #pragma unroll
            for (int i = 0; i < 4; ++i)
                #pragma unroll
                for (int j = 0; j < 4; ++j)
                    acc[i][j] = __builtin_amdgcn_mfma_f32_16x16x32_bf16(af[i], bfv[j], acc[i][j], 0, 0, 0);
        }
        __syncthreads();
    }
    if constexpr (sizeof(CT) == 4) {
        #pragma unroll
        for (int i = 0; i < 4; ++i)
            #pragma unroll
            for (int j = 0; j < 4; ++j)
                #pragma unroll
                for (int q = 0; q < 4; ++q) {
                    int rr = m0 + wr * 64 + i * 16 + (lane >> 4) * 4 + q;
                    int cc = n0 + wc * 64 + j * 16 + (lane & 15);
                    C[(size_t)rr * N + cc] = acc[i][j][q];
                }
    } else {
        ushort (*Tile)[TILEC] = (ushort (*)[TILEC])LB;
        #pragma unroll
        for (int i = 0; i < 4; ++i)
            #pragma unroll
            for (int j = 0; j < 4; ++j)
                #pragma unroll
                for (int q = 0; q < 4; ++q)
                    Tile[wr * 64 + i * 16 + (lane >> 4) * 4 + q]
                        [wc * 64 + j * 16 + (lane & 15)] = f2bf(acc[i][j][q]);
        __syncthreads();
        #pragma unroll
        for (int it = 0; it < 8; ++it) {
            int idx = tid + it * 256;
            int rr = idx >> 4, g = idx & 15;
            *(uint4*)&C[(size_t)(m0 + rr) * N + n0 + g * 8] = *(uint4*)&Tile[rr][g * 8];
        }
    }
}

// ------------------- depthwise conv + SiLU: LDS weights, 4 t-steps/thread
__global__ __launch_bounds__(256) void conv_silu_k(const ushort* __restrict__ zx,
                                                   const float* __restrict__ cw,
                                                   const float* __restrict__ cb,
                                                   ushort* __restrict__ out) {
    __shared__ float cws[KCONV][CONVDIM];
    __shared__ float cbs[CONVDIM];
    const int tid = threadIdx.x;
    #pragma unroll
    for (int it = 0; it < 3; ++it) {
        int i = tid + it * 256;
        cbs[i] = cb[i];
        #pragma unroll
        for (int k = 0; k < KCONV; ++k) cws[k][i] = cw[i * KCONV + k];
    }
    __syncthreads();

    const int idx = blockIdx.x * 256 + tid;
    const int cg = idx % 96, btq = idx / 96;
    const int c0 = cg * 8;
    const int bt0 = btq * 4;
    const int t0 = bt0 & (SEQ - 1);

    float wv[KCONV][8], bias[8];
    #pragma unroll
    for (int j = 0; j < 8; ++j) bias[j] = cbs[c0 + j];
    #pragma unroll
    for (int k = 0; k < KCONV; ++k) {
        float4 a = *(const float4*)&cws[k][c0];
        float4 b = *(const float4*)&cws[k][c0 + 4];
        wv[k][0] = a.x; wv[k][1] = a.y; wv[k][2] = a.z; wv[k][3] = a.w;
        wv[k][4] = b.x; wv[k][5] = b.y; wv[k][6] = b.z; wv[k][7] = b.w;
    }
    float xr[7][8];
    #pragma unroll
    for (int r = 0; r < 7; ++r) {
        int tt = t0 - 3 + r;
        if (tt >= 0) {
            uint4 v = *(const uint4*)&zx[(size_t)(bt0 - 3 + r) * ZXLD + DINNER + c0];
            const ushort* pv = (const ushort*)&v;
            #pragma unroll
            for (int j = 0; j < 8; ++j) xr[r][j] = bf2f(pv[j]);
        } else {
            #pragma unroll
            for (int j = 0; j < 8; ++j) xr[r][j] = 0.f;
        }
    }
    #pragma unroll
    for (int dt = 0; dt < 4; ++dt) {
        float acc[8];
        #pragma unroll
        for (int j = 0; j < 8; ++j) acc[j] = bias[j];
        #pragma unroll
        for (int k = 0; k < KCONV; ++k)
            #pragma unroll
            for (int j = 0; j < 8; ++j) acc[j] += xr[dt + k][j] * wv[k][j];
        ushort res[8];
        #pragma unroll
        for (int j = 0; j < 8; ++j)
            res[j] = f2bf(acc[j] / (1.f + __expf(-acc[j])));
        *(uint4*)&out[(size_t)(bt0 + dt) * CONVDIM + c0] = *(uint4*)res;
    }
}

// -------------------------------------------------- SSD MFMA kernel (XCD-swizzled)
#define SLDA 136
#define SLDB 72
__global__ __launch_bounds__(256) void ssd_mfma_k(const ushort* __restrict__ xbc,
                                                  const float* __restrict__ dtb,
                                                  const float* __restrict__ adtb,
                                                  const float* __restrict__ Dp,
                                                  ushort* __restrict__ ybuf,
                                                  ushort* __restrict__ states,
                                                  float* __restrict__ acsbuf,
                                                  float* __restrict__ chunksum) {
    const int wk = (blockIdx.x & 7) * 64 + (blockIdx.x >> 3);
    const int hgrp = wk & 1, c = (wk >> 1) & 15, b = wk >> 5;
    const int row0 = b * SEQ + c * LCHUNK;
    const int tid = threadIdx.x;
    const int lane = tid & 63, w = tid >> 6;
    const int fr = lane & 15, kc = lane >> 4;

    __shared__ union {
        struct { ushort Bs[64][SLDA]; ushort Cs[64][SLDA]; } p1;
        struct { ushort Ps[64][SLDB]; ushort Xt[64][SLDB]; ushort Xdt[64][SLDB]; } p2;
    } U;
    __shared__ ushort Btr[128][SLDB];
    __shared__ float acs4[4][64];
    __shared__ float dts[4][64];
    __shared__ float decs[4][64];

    {
        const int hh = hgrp * 4 + w;
        float v = adtb[(size_t)(row0 + lane) * NHEADS + hh];
        #pragma unroll
        for (int off = 1; off < 64; off <<= 1) {
            float t = __shfl_up(v, off);
            if (lane >= off) v += t;
        }
        acs4[w][lane] = v;
        float tot = __shfl(v, 63);
        decs[w][lane] = __expf(tot - v);
        acsbuf[(((size_t)b * NCHUNK + c) * NHEADS + hh) * LCHUNK + lane] = v;
        if (lane == 63) chunksum[((size_t)b * NCHUNK + c) * NHEADS + hh] = v;
        dts[w][lane] = dtb[(size_t)(row0 + lane) * NHEADS + hh];
    }
    for (int it = 0; it < 4; ++it) {
        int idx = tid + it * 256;
        int l = idx >> 4, ng = idx & 15;
        const ushort* rp = &xbc[(size_t)(row0 + l) * CONVDIM + DINNER];
        uint4 vb = *(const uint4*)(rp + ng * 8);
        *(uint4*)&U.p1.Bs[l][ng * 8] = vb;
        uint4 vc = *(const uint4*)(rp + DSTATE + ng * 8);
        *(uint4*)&U.p1.Cs[l][ng * 8] = vc;
        const ushort* pv = (const ushort*)&vb;
        #pragma unroll
        for (int j = 0; j < 8; ++j) Btr[ng * 8 + j][l] = pv[j];
    }
    __syncthreads();

    const int wr = w >> 1, wc = w & 1;
    f32x4 accG[2][2];
    #pragma unroll
    for (int i = 0; i < 2; ++i)
        #pragma unroll
        for (int j = 0; j < 2; ++j) accG[i][j] = (f32x4)0.f;
    #pragma unroll
    for (int kt = 0; kt < 4; ++kt) {
        bf16x8 af[2], bfv[2];
        #pragma unroll
        for (int i = 0; i < 2; ++i) af[i]  = *(const bf16x8*)&U.p1.Cs[wr*32 + i*16 + fr][kt*32 + kc*8];
        #pragma unroll
        for (int j = 0; j < 2; ++j) bfv[j] = *(const bf16x8*)&U.p1.Bs[wc*32 + j*16 + fr][kt*32 + kc*8];
        #pragma unroll
        for (int i = 0; i < 2; ++i)
            #pragma unroll
            for (int j = 0; j < 2; ++j)
                accG[i][j] = __builtin_amdgcn_mfma_f32_16x16x32_bf16(af[i], bfv[j], accG[i][j], 0, 0, 0);
    }
    __syncthreads();

    for (int hl = 0; hl < 4; ++hl) {
        const int hh = hgrp * 4 + hl;
        {
            const int p = lane;
            ushort xt[16], xdt[16];
            #pragma unroll
            for (int j = 0; j < 16; ++j) {
                int l = w * 16 + j;
                float xv = bf2f(xbc[(size_t)(row0 + l) * CONVDIM + hh * HEADDIM + p])
                           * dts[hl][l];
                xt[j]  = f2bf(xv);
                xdt[j] = f2bf(xv * decs[hl][l]);
            }
            #pragma unroll
            for (int v = 0; v < 4; ++v) {
                *(ushort4*)&U.p2.Xt [p][w*16 + v*4] = *(ushort4*)&xt[v*4];
                *(ushort4*)&U.p2.Xdt[p][w*16 + v*4] = *(ushort4*)&xdt[v*4];
            }
        }
        #pragma unroll
        for (int i = 0; i < 2; ++i)
            #pragma unroll
            for (int j = 0; j < 2; ++j)
                #pragma unroll
                for (int q = 0; q < 4; ++q) {
                    int l = wr*32 + i*16 + (lane >> 4)*4 + q;
                    int s = wc*32 + j*16 + fr;
                    float v = 0.f;
                    if (s < l)       v = accG[i][j][q] * __expf(acs4[hl][l] - acs4[hl][s]);
                    else if (s == l) v = accG[i][j][q] + Dp[hh] / dts[hl][l];
                    U.p2.Ps[l][s] = f2bf(v);
                }
        __syncthreads();
        {
            f32x4 acc[4];
            #pragma unroll
            for (int j = 0; j < 4; ++j) acc[j] = (f32x4)0.f;
            #pragma unroll
            for (int kt = 0; kt < 2; ++kt) {
                bf16x8 af = *(const bf16x8*)&U.p2.Ps[w*16 + fr][kt*32 + kc*8];
                #pragma unroll
                for (int j = 0; j < 4; ++j) {
                    bf16x8 bfv = *(const bf16x8*)&U.p2.Xt[j*16 + fr][kt*32 + kc*8];
                    acc[j] = __builtin_amdgcn_mfma_f32_16x16x32_bf16(af, bfv, acc[j], 0, 0, 0);
                }
            }
            #pragma unroll
            for (int j = 0; j < 4; ++j)
                #pragma unroll
                for (int q = 0; q < 4; ++q) {
                    int l = w*16 + (lane >> 4)*4 + q;
                    int p = j*16 + fr;
                    ybuf[(size_t)(row0 + l) * DINNER + hh * HEADDIM + p] = f2bf(acc[j][q]);
                }
        }
        {
            f32x4 acc2[4][2];
            #pragma unroll
            for (int mt = 0; mt < 4; ++mt)
                #pragma unroll
                for (int jt = 0; jt < 2; ++jt) acc2[mt][jt] = (f32x4)0.f;
            #pragma unroll
            for (int kt = 0; kt < 2; ++kt) {
                bf16x8 a4[4], b2[2];
                #pragma unroll
                for (int mt = 0; mt < 4; ++mt) a4[mt] = *(const bf16x8*)&U.p2.Xdt[mt*16 + fr][kt*32 + kc*8];
                #pragma unroll
                for (int jt = 0; jt < 2; ++jt) b2[jt] = *(const bf16x8*)&Btr[w*32 + jt*16 + fr][kt*32 + kc*8];
                #pragma unroll
                for (int mt = 0; mt < 4; ++mt)
                    #pragma unroll
                    for (int jt = 0; jt < 2; ++jt)
                        acc2[mt][jt] = __builtin_amdgcn_mfma_f32_16x16x32_bf16(a4[mt], b2[jt], acc2[mt][jt], 0, 0, 0);
            }
            ushort* sb = states + ((((size_t)b * NCHUNK + c) * NHEADS + hh) * HEADDIM) * DSTATE;
            #pragma unroll
            for (int mt = 0; mt < 4; ++mt)
                #pragma unroll
                for (int jt = 0; jt < 2; ++jt)
                    #pragma unroll
                    for (int q = 0; q < 4; ++q) {
                        int p = mt*16 + (lane >> 4)*4 + q;
                        int n = w*32 + jt*16 + fr;
                        sb[(size_t)p * DSTATE + n] = f2bf(acc2[mt][jt][q]);
                    }
        }
        __syncthreads();
    }
}

// ------------------------------------- inter-chunk scan (bf16 states, f32 regs)
__global__ __launch_bounds__(256) void scan_k(ushort* __restrict__ states,
                                              const float* __restrict__ chunksum) {
    const int bid = blockIdx.x;
    const int pq = bid & 3, h = (bid >> 2) & 7, b = bid >> 5;
    const int tid = threadIdx.x;
    float pref[8];
    #pragma unroll
    for (int k = 0; k < 8; ++k) pref[k] = 0.f;
    for (int c = 0; c < NCHUNK; ++c) {
        ushort* base = states + (((size_t)b * NCHUNK + c) * NHEADS + h) * (HEADDIM * DSTATE)
                       + pq * 2048 + tid * 8;
        float dec = __expf(chunksum[((size_t)b * NCHUNK + c) * NHEADS + h]);
        uint4 v = *(const uint4*)base;
        const ushort* pv = (const ushort*)&v;
        ushort outv[8];
        #pragma unroll
        for (int j = 0; j < 8; ++j) {
            float cur = bf2f(pv[j]);
            outv[j] = f2bf(pref[j]);
            pref[j] = dec * pref[j] + cur;
        }
        *(uint4*)base = *(uint4*)outv;
    }
}

// ----- Y_off + gate + RMSNorm, 32-row blocks (512 blocks, XCD-chunked)
__global__ __launch_bounds__(256) void yoff_gate_k(const ushort* __restrict__ xbc,
                                                   const ushort* __restrict__ states,
                                                   const float* __restrict__ acsbuf,
                                                   const ushort* __restrict__ ybuf,
                                                   const ushort* __restrict__ zx,
                                                   const float* __restrict__ nw,
                                                   ushort* __restrict__ gbuf) {
    const int wk = (blockIdx.x & 7) * 64 + (blockIdx.x >> 3);
    const int half = wk & 1, c = (wk >> 1) & 15, b = wk >> 5;
    const int row0 = b * SEQ + c * LCHUNK + half * 32;
    const int tid = threadIdx.x;
    const int lane = tid & 63, w = tid >> 6;
    const int fr = lane & 15, kc = lane >> 4;
    const int rw = (w & 1) * 16;           // wave row range (16 of 32)
    const int j0 = (w >> 1) * 2;           // wave col-frag pair
    __shared__ ushort Csh[32][SLDA];
    __shared__ ushort Ssh[64][SLDA];
    __shared__ ushort Ys[32][520];
    __shared__ float eah[32];

    #pragma unroll
    for (int it = 0; it < 2; ++it) {
        int idx = tid + it * 256;          // 512 grains: l(32) x ng(16)
        int l = idx >> 4, ng = idx & 15;
        *(uint4*)&Csh[l][ng * 8] =
            *(const uint4*)&xbc[(size_t)(row0 + l) * CONVDIM + DINNER + DSTATE + ng * 8];
    }
    for (int hl = 0; hl < NHEADS; ++hl) {
        __syncthreads();
        const ushort* sb = states + ((((size_t)b * NCHUNK + c) * NHEADS + hl) * HEADDIM) * DSTATE;
        #pragma unroll
        for (int it = 0; it < 4; ++it) {
            int idx = tid + it * 256;
            int p = idx >> 4, ng = idx & 15;
            *(uint4*)&Ssh[p][ng * 8] = *(const uint4*)&sb[(size_t)p * DSTATE + ng * 8];
        }
        if (tid < 32)
            eah[tid] = __expf(acsbuf[(((size_t)b * NCHUNK + c) * NHEADS + hl) * LCHUNK
                                     + half * 32 + tid]);
        __syncthreads();
        f32x4 acc[2];
        acc[0] = (f32x4)0.f; acc[1] = (f32x4)0.f;
        #pragma unroll
        for (int kt = 0; kt < 4; ++kt) {
            bf16x8 af = *(const bf16x8*)&Csh[rw + fr][kt*32 + kc*8];
            #pragma unroll
            for (int jj = 0; jj < 2; ++jj) {
                bf16x8 bfv = *(const bf16x8*)&Ssh[(j0+jj)*16 + fr][kt*32 + kc*8];
                acc[jj] = __builtin_amdgcn_mfma_f32_16x16x32_bf16(af, bfv, acc[jj], 0, 0, 0);
            }
        }
        #pragma unroll
        for (int jj = 0; jj < 2; ++jj)
            #pragma unroll
            for (int q = 0; q < 4; ++q) {
                int l = rw + (lane >> 4)*4 + q;
                int p = (j0+jj)*16 + fr;
                float val = bf2f(ybuf[(size_t)(row0 + l) * DINNER + hl * HEADDIM + p])
                            + acc[jj][q] * eah[l];
                Ys[l][hl * HEADDIM + p] = f2bf(val);
            }
    }
    __syncthreads();
    float nwv[8];
    #pragma unroll
    for (int j = 0; j < 8; ++j) nwv[j] = nw[lane * 8 + j];
    #pragma unroll
    for (int i = 0; i < 8; ++i) {
        int l = w * 8 + i;
        int row = row0 + l;
        uint4 zv = *(const uint4*)&zx[(size_t)row * ZXLD + lane * 8];
        const ushort* pz = (const ushort*)&zv;
        float g[8], ss = 0.f;
        #pragma unroll
        for (int j = 0; j < 8; ++j) {
            float y = bf2f(Ys[l][lane * 8 + j]);
            float z = bf2f(pz[j]);
            float sz = z / (1.f + __expf(-z));
            g[j] = y * sz;
            ss += g[j] * g[j];
        }
        #pragma unroll
        for (int off = 32; off; off >>= 1) ss += __shfl_xor(ss, off);
        float r = rsqrtf(ss / (float)DINNER + EPSV);
        ushort res[8];
        #pragma unroll
        for (int j = 0; j < 8; ++j) res[j] = f2bf(g[j] * r * nwv[j]);
        *(uint4*)&gbuf[(size_t)row * DINNER + lane * 8] = *(uint4*)res;
    }
}

// ---------------------------------------------------------------- launch
extern "C" void kernel_launch(void* const* d_in, const int* in_sizes, int n_in,
                              void* d_out, int out_size, void* d_ws, size_t ws_size,
                              hipStream_t stream) {
    const float* u       = (const float*)d_in[0];
    const float* W_in    = (const float*)d_in[1];
    const float* conv_w  = (const float*)d_in[2];
    const float* conv_b  = (const float*)d_in[3];
    const float* dt_bias = (const float*)d_in[4];
    const float* A_log   = (const float*)d_in[5];
    const float* Dp      = (const float*)d_in[6];
    const float* norm_w  = (const float*)d_in[7];
    const float* W_out   = (const float*)d_in[8];
    float* out = (float*)d_out;

    char* p = (char*)d_ws;
    ushort* zx       = (ushort*)p; p += (size_t)ROWS * ZXLD * sizeof(ushort);
    ushort* ybuf     = (ushort*)p; p += (size_t)ROWS * DINNER * sizeof(ushort);
    ushort* gbuf     = (ushort*)p; p += (size_t)ROWS * DINNER * sizeof(ushort);
    ushort* states   = (ushort*)p; p += (size_t)BATCHN * NCHUNK * NHEADS * HEADDIM * DSTATE * sizeof(ushort);
    ushort* xbc      = (ushort*)p; p += (size_t)ROWS * CONVDIM * sizeof(ushort);
    ushort* ubf      = (ushort*)p; p += (size_t)ROWS * DMODEL * sizeof(ushort);
    float*  dtb      = (float*)p;  p += (size_t)ROWS * NHEADS  * sizeof(float);
    float*  adtb     = (float*)p;  p += (size_t)ROWS * NHEADS  * sizeof(float);
    float*  chunksum = (float*)p;  p += (size_t)BATCHN * NCHUNK * NHEADS * sizeof(float);
    float*  acsbuf   = (float*)p;  p += (size_t)BATCHN * NCHUNK * NHEADS * LCHUNK * sizeof(float);
    ushort* WtA      = (ushort*)p; p += (size_t)ZXLD * DMODEL * sizeof(ushort);
    ushort* WtB      = (ushort*)p; p += (size_t)DMODEL * DINNER * sizeof(ushort);

    prep_k<<<960, 256, 0, stream>>>(u, W_in, W_out, dt_bias, A_log,
                                    ubf, dtb, adtb, WtA, WtB);
    gemm_bf16<ushort><<<(ZXLD/128)*(ROWS/128), 256, 0, stream>>>(
        ubf, WtA, zx, ROWS, ZXLD, DMODEL, ZXLD/128);
    conv_silu_k<<<(ROWS/4)*96/256, 256, 0, stream>>>(zx, conv_w, conv_b, xbc);
    ssd_mfma_k<<<512, 256, 0, stream>>>(
        xbc, dtb, adtb, Dp, ybuf, states, acsbuf, chunksum);
    scan_k<<<BATCHN*NHEADS*4, 256, 0, stream>>>(states, chunksum);
    yoff_gate_k<<<512, 256, 0, stream>>>(
        xbc, states, acsbuf, ybuf, zx, norm_w, gbuf);
    gemm_bf16<float><<<(DMODEL/128)*(ROWS/128), 256, 0, stream>>>(
        gbuf, WtB, out, ROWS, DMODEL, DINNER, DMODEL/128);
}

// Round 16
// 120.513 us; speedup vs baseline: 1.0661x; 1.0397x over previous
//
#include <hip/hip_runtime.h>
#include <hip/hip_bf16.h>
#include <math.h>

#define BATCHN  16
#define SEQ     1024
#define DMODEL  256
#define DSTATE  128
#define HEADDIM 64
#define DINNER  512
#define NHEADS  8
#define CONVDIM 768
#define DINPROJ 1288
#define ZXLD    1280
#define KCONV   4
#define NCHUNK  16
#define LCHUNK  64
#define EPSV    1e-5f
#define ROWS    (BATCHN*SEQ)

typedef __attribute__((ext_vector_type(8))) __bf16 bf16x8;
typedef __attribute__((ext_vector_type(4))) float  f32x4;

__device__ inline ushort f2bf(float f) {
    union { float f; uint32_t u; } v; v.f = f;
    uint32_t r = v.u + 0x7fff + ((v.u >> 16) & 1);
    return (ushort)(r >> 16);
}
__device__ inline float bf2f(ushort u) {
    union { uint32_t u; float f; } v; v.u = ((uint32_t)u) << 16;
    return v.f;
}

// ---------- prep: dt GEMV + u->bf16 cast (blocks 0..511) | W transposes (512..959)
__global__ __launch_bounds__(256) void prep_k(const float* __restrict__ u,
                                              const float* __restrict__ W_in,
                                              const float* __restrict__ W_out,
                                              const float* __restrict__ dt_bias,
                                              const float* __restrict__ A_log,
                                              ushort* __restrict__ ubf,
                                              float* __restrict__ dtb,
                                              float* __restrict__ adtb,
                                              ushort* __restrict__ WtA,
                                              ushort* __restrict__ WtB) {
    __shared__ union {
        struct { float Uld[32][264]; float Ws[DMODEL][NHEADS]; } d;
        float Ts[32][33];
    } S;
    const int tid = threadIdx.x;
    if (blockIdx.x < 512) {
        #pragma unroll
        for (int j = 0; j < 8; ++j) {
            int idx = tid + j * 256;
            S.d.Ws[idx >> 3][idx & 7] = W_in[(size_t)(idx >> 3) * DINPROJ + 1280 + (idx & 7)];
        }
        const int row0 = blockIdx.x * 32;
        #pragma unroll
        for (int v = 0; v < 8; ++v) {
            int e = v * 1024 + tid * 4;
            int r = e >> 8, cc = e & 255;
            float4 x = *(const float4*)&u[(size_t)(row0 + r) * DMODEL + cc];
            *(float4*)&S.d.Uld[r][cc] = x;
            ushort t4[4];
            t4[0]=f2bf(x.x); t4[1]=f2bf(x.y); t4[2]=f2bf(x.z); t4[3]=f2bf(x.w);
            *(ushort4*)&ubf[(size_t)(row0 + r) * DMODEL + cc] = *(ushort4*)t4;
        }
        __syncthreads();
        const int row = tid >> 3, h = tid & 7;
        float acc = 0.f;
        #pragma unroll 8
        for (int k = 0; k < DMODEL; k += 4) {
            float4 uv = *(const float4*)&S.d.Uld[row][k];
            acc += uv.x * S.d.Ws[k][h] + uv.y * S.d.Ws[k+1][h]
                 + uv.z * S.d.Ws[k+2][h] + uv.w * S.d.Ws[k+3][h];
        }
        float v = acc + dt_bias[h];
        float dt = (v > 20.f) ? v : log1pf(__expf(v));
        dtb [(size_t)(row0 + row) * NHEADS + h] = dt;
        adtb[(size_t)(row0 + row) * NHEADS + h] = dt * (-__expf(A_log[h]));
    } else {
        int bid = blockIdx.x - 512;
        const float* src; ushort* dst; int K, ldsrc, nx;
        if (bid < 320) { src = W_in;  dst = WtA; K = DMODEL; ldsrc = DINPROJ; nx = 40; }
        else { bid -= 320; src = W_out; dst = WtB; K = DINNER; ldsrc = DMODEL; nx = 8; }
        const int n0 = (bid % nx) * 32, k0 = (bid / nx) * 32;
        const int tx = tid & 31, ty = tid >> 5;
        #pragma unroll
        for (int j = 0; j < 4; ++j) {
            int kl = ty * 4 + j;
            S.Ts[kl][tx] = src[(size_t)(k0 + kl) * ldsrc + n0 + tx];
        }
        __syncthreads();
        #pragma unroll
        for (int j = 0; j < 4; ++j) {
            int nl = ty * 4 + j;
            dst[(size_t)(n0 + nl) * K + k0 + tx] = f2bf(S.Ts[tx][nl]);
        }
    }
}

// ------------------------------------------------------- bf16 MFMA GEMM
// bf16 output path repacks the tile through LDS -> uint4 stores.
#define LDSW 72
#define TILEC 132
__global__ __launch_bounds__(256) void gemm_bf16(const ushort* __restrict__ A,
                                                 const ushort* __restrict__ Bt,
                                                 ushort* __restrict__ C,
                                                 int M, int N, int K, int nx) {
    __shared__ ushort LB[2 * 128 * LDSW];
    ushort* As = LB;
    ushort* Bs = LB + 128 * LDSW;
    const int tid  = threadIdx.x;
    const int nwg  = gridDim.x;
    const int work = (blockIdx.x & 7) * (nwg >> 3) + (blockIdx.x >> 3);
    const int m0 = (work / nx) * 128, n0 = (work % nx) * 128;
    const int wid = tid >> 6, lane = tid & 63;
    const int wr = wid >> 1, wc = wid & 1;
    const int r = tid >> 1, kq = tid & 1;
    const int fr = lane & 15, kc = lane >> 4;

    f32x4 acc[4][4];
    #pragma unroll
    for (int i = 0; i < 4; ++i)
        #pragma unroll
        for (int j = 0; j < 4; ++j) acc[i][j] = (f32x4)0.f;

    for (int kt = 0; kt < K; kt += 64) {
        const ushort* ap = &A [(size_t)(m0 + r) * K + kt + kq * 32];
        const ushort* bp = &Bt[(size_t)(n0 + r) * K + kt + kq * 32];
        #pragma unroll
        for (int v = 0; v < 4; ++v) {
            *(uint4*)&As[r * LDSW + kq * 32 + v * 8] = *(const uint4*)(ap + v * 8);
            *(uint4*)&Bs[r * LDSW + kq * 32 + v * 8] = *(const uint4*)(bp + v * 8);
        }
        __syncthreads();
        #pragma unroll
        for (int kk = 0; kk < 2; ++kk) {
            bf16x8 af[4], bfv[4];
            #pragma unroll
            for (int i = 0; i < 4; ++i) {
                af[i]  = *(const bf16x8*)&As[(wr * 64 + i * 16 + fr) * LDSW + kk * 32 + kc * 8];
                bfv[i] = *(const bf16x8*)&Bs[(wc * 64 + i * 16 + fr) * LDSW + kk * 32 + kc * 8];
            }
            #pragma unroll
            for (int i = 0; i < 4; ++i)
                #pragma unroll
                for (int j = 0; j < 4; ++j)
                    acc[i][j] = __builtin_amdgcn_mfma_f32_16x16x32_bf16(af[i], bfv[j], acc[i][j], 0, 0, 0);
        }
        __syncthreads();
    }
    ushort (*Tile)[TILEC] = (ushort (*)[TILEC])LB;
    #pragma unroll
    for (int i = 0; i < 4; ++i)
        #pragma unroll
        for (int j = 0; j < 4; ++j)
            #pragma unroll
            for (int q = 0; q < 4; ++q)
                Tile[wr * 64 + i * 16 + (lane >> 4) * 4 + q]
                    [wc * 64 + j * 16 + (lane & 15)] = f2bf(acc[i][j][q]);
    __syncthreads();
    #pragma unroll
    for (int it = 0; it < 8; ++it) {
        int idx = tid + it * 256;
        int rr = idx >> 4, g = idx & 15;
        *(uint4*)&C[(size_t)(m0 + rr) * N + n0 + g * 8] = *(uint4*)&Tile[rr][g * 8];
    }
}

// ------------------- depthwise conv + SiLU: LDS weights, 4 t-steps/thread
__global__ __launch_bounds__(256) void conv_silu_k(const ushort* __restrict__ zx,
                                                   const float* __restrict__ cw,
                                                   const float* __restrict__ cb,
                                                   ushort* __restrict__ out) {
    __shared__ float cws[KCONV][CONVDIM];
    __shared__ float cbs[CONVDIM];
    const int tid = threadIdx.x;
    #pragma unroll
    for (int it = 0; it < 3; ++it) {
        int i = tid + it * 256;
        cbs[i] = cb[i];
        #pragma unroll
        for (int k = 0; k < KCONV; ++k) cws[k][i] = cw[i * KCONV + k];
    }
    __syncthreads();

    const int idx = blockIdx.x * 256 + tid;
    const int cg = idx % 96, btq = idx / 96;
    const int c0 = cg * 8;
    const int bt0 = btq * 4;
    const int t0 = bt0 & (SEQ - 1);

    float wv[KCONV][8], bias[8];
    #pragma unroll
    for (int j = 0; j < 8; ++j) bias[j] = cbs[c0 + j];
    #pragma unroll
    for (int k = 0; k < KCONV; ++k) {
        float4 a = *(const float4*)&cws[k][c0];
        float4 b = *(const float4*)&cws[k][c0 + 4];
        wv[k][0] = a.x; wv[k][1] = a.y; wv[k][2] = a.z; wv[k][3] = a.w;
        wv[k][4] = b.x; wv[k][5] = b.y; wv[k][6] = b.z; wv[k][7] = b.w;
    }
    float xr[7][8];
    #pragma unroll
    for (int r = 0; r < 7; ++r) {
        int tt = t0 - 3 + r;
        if (tt >= 0) {
            uint4 v = *(const uint4*)&zx[(size_t)(bt0 - 3 + r) * ZXLD + DINNER + c0];
            const ushort* pv = (const ushort*)&v;
            #pragma unroll
            for (int j = 0; j < 8; ++j) xr[r][j] = bf2f(pv[j]);
        } else {
            #pragma unroll
            for (int j = 0; j < 8; ++j) xr[r][j] = 0.f;
        }
    }
    #pragma unroll
    for (int dt = 0; dt < 4; ++dt) {
        float acc[8];
        #pragma unroll
        for (int j = 0; j < 8; ++j) acc[j] = bias[j];
        #pragma unroll
        for (int k = 0; k < KCONV; ++k)
            #pragma unroll
            for (int j = 0; j < 8; ++j) acc[j] += xr[dt + k][j] * wv[k][j];
        ushort res[8];
        #pragma unroll
        for (int j = 0; j < 8; ++j)
            res[j] = f2bf(acc[j] / (1.f + __expf(-acc[j])));
        *(uint4*)&out[(size_t)(bt0 + dt) * CONVDIM + c0] = *(uint4*)res;
    }
}

// -------------------------------------------------- SSD MFMA kernel (XCD-swizzled)
#define SLDA 136
#define SLDB 72
__global__ __launch_bounds__(256) void ssd_mfma_k(const ushort* __restrict__ xbc,
                                                  const float* __restrict__ dtb,
                                                  const float* __restrict__ adtb,
                                                  const float* __restrict__ Dp,
                                                  ushort* __restrict__ ybuf,
                                                  ushort* __restrict__ states,
                                                  float* __restrict__ acsbuf,
                                                  float* __restrict__ chunksum) {
    const int wk = (blockIdx.x & 7) * 64 + (blockIdx.x >> 3);
    const int hgrp = wk & 1, c = (wk >> 1) & 15, b = wk >> 5;
    const int row0 = b * SEQ + c * LCHUNK;
    const int tid = threadIdx.x;
    const int lane = tid & 63, w = tid >> 6;
    const int fr = lane & 15, kc = lane >> 4;

    __shared__ union {
        struct { ushort Bs[64][SLDA]; ushort Cs[64][SLDA]; } p1;
        struct { ushort Ps[64][SLDB]; ushort Xt[64][SLDB]; ushort Xdt[64][SLDB]; } p2;
    } U;
    __shared__ ushort Btr[128][SLDB];
    __shared__ float acs4[4][64];
    __shared__ float dts[4][64];
    __shared__ float decs[4][64];

    {
        const int hh = hgrp * 4 + w;
        float v = adtb[(size_t)(row0 + lane) * NHEADS + hh];
        #pragma unroll
        for (int off = 1; off < 64; off <<= 1) {
            float t = __shfl_up(v, off);
            if (lane >= off) v += t;
        }
        acs4[w][lane] = v;
        float tot = __shfl(v, 63);
        decs[w][lane] = __expf(tot - v);
        acsbuf[(((size_t)b * NCHUNK + c) * NHEADS + hh) * LCHUNK + lane] = v;
        if (lane == 63) chunksum[((size_t)b * NCHUNK + c) * NHEADS + hh] = v;
        dts[w][lane] = dtb[(size_t)(row0 + lane) * NHEADS + hh];
    }
    for (int it = 0; it < 4; ++it) {
        int idx = tid + it * 256;
        int l = idx >> 4, ng = idx & 15;
        const ushort* rp = &xbc[(size_t)(row0 + l) * CONVDIM + DINNER];
        uint4 vb = *(const uint4*)(rp + ng * 8);
        *(uint4*)&U.p1.Bs[l][ng * 8] = vb;
        uint4 vc = *(const uint4*)(rp + DSTATE + ng * 8);
        *(uint4*)&U.p1.Cs[l][ng * 8] = vc;
        const ushort* pv = (const ushort*)&vb;
        #pragma unroll
        for (int j = 0; j < 8; ++j) Btr[ng * 8 + j][l] = pv[j];
    }
    __syncthreads();

    const int wr = w >> 1, wc = w & 1;
    f32x4 accG[2][2];
    #pragma unroll
    for (int i = 0; i < 2; ++i)
        #pragma unroll
        for (int j = 0; j < 2; ++j) accG[i][j] = (f32x4)0.f;
    #pragma unroll
    for (int kt = 0; kt < 4; ++kt) {
        bf16x8 af[2], bfv[2];
        #pragma unroll
        for (int i = 0; i < 2; ++i) af[i]  = *(const bf16x8*)&U.p1.Cs[wr*32 + i*16 + fr][kt*32 + kc*8];
        #pragma unroll
        for (int j = 0; j < 2; ++j) bfv[j] = *(const bf16x8*)&U.p1.Bs[wc*32 + j*16 + fr][kt*32 + kc*8];
        #pragma unroll
        for (int i = 0; i < 2; ++i)
            #pragma unroll
            for (int j = 0; j < 2; ++j)
                accG[i][j] = __builtin_amdgcn_mfma_f32_16x16x32_bf16(af[i], bfv[j], accG[i][j], 0, 0, 0);
    }
    __syncthreads();

    for (int hl = 0; hl < 4; ++hl) {
        const int hh = hgrp * 4 + hl;
        {
            const int p = lane;
            ushort xt[16], xdt[16];
            #pragma unroll
            for (int j = 0; j < 16; ++j) {
                int l = w * 16 + j;
                float xv = bf2f(xbc[(size_t)(row0 + l) * CONVDIM + hh * HEADDIM + p])
                           * dts[hl][l];
                xt[j]  = f2bf(xv);
                xdt[j] = f2bf(xv * decs[hl][l]);
            }
            #pragma unroll
            for (int v = 0; v < 4; ++v) {
                *(ushort4*)&U.p2.Xt [p][w*16 + v*4] = *(ushort4*)&xt[v*4];
                *(ushort4*)&U.p2.Xdt[p][w*16 + v*4] = *(ushort4*)&xdt[v*4];
            }
        }
        #pragma unroll
        for (int i = 0; i < 2; ++i)
            #pragma unroll
            for (int j = 0; j < 2; ++j)
                #pragma unroll
                for (int q = 0; q < 4; ++q) {
                    int l = wr*32 + i*16 + (lane >> 4)*4 + q;
                    int s = wc*32 + j*16 + fr;
                    float v = 0.f;
                    if (s < l)       v = accG[i][j][q] * __expf(acs4[hl][l] - acs4[hl][s]);
                    else if (s == l) v = accG[i][j][q] + Dp[hh] / dts[hl][l];
                    U.p2.Ps[l][s] = f2bf(v);
                }
        __syncthreads();
        {
            f32x4 acc[4];
            #pragma unroll
            for (int j = 0; j < 4; ++j) acc[j] = (f32x4)0.f;
            #pragma unroll
            for (int kt = 0; kt < 2; ++kt) {
                bf16x8 af = *(const bf16x8*)&U.p2.Ps[w*16 + fr][kt*32 + kc*8];
                #pragma unroll
                for (int j = 0; j < 4; ++j) {
                    bf16x8 bfv = *(const bf16x8*)&U.p2.Xt[j*16 + fr][kt*32 + kc*8];
                    acc[j] = __builtin_amdgcn_mfma_f32_16x16x32_bf16(af, bfv, acc[j], 0, 0, 0);
                }
            }
            #pragma unroll
            for (int j = 0; j < 4; ++j)
                #pragma unroll
                for (int q = 0; q < 4; ++q) {
                    int l = w*16 + (lane >> 4)*4 + q;
                    int p = j*16 + fr;
                    ybuf[(size_t)(row0 + l) * DINNER + hh * HEADDIM + p] = f2bf(acc[j][q]);
                }
        }
        {
            f32x4 acc2[4][2];
            #pragma unroll
            for (int mt = 0; mt < 4; ++mt)
                #pragma unroll
                for (int jt = 0; jt < 2; ++jt) acc2[mt][jt] = (f32x4)0.f;
            #pragma unroll
            for (int kt = 0; kt < 2; ++kt) {
                bf16x8 a4[4], b2[2];
                #pragma unroll
                for (int mt = 0; mt < 4; ++mt) a4[mt] = *(const bf16x8*)&U.p2.Xdt[mt*16 + fr][kt*32 + kc*8];
                #pragma unroll
                for (int jt = 0; jt < 2; ++jt) b2[jt] = *(const bf16x8*)&Btr[w*32 + jt*16 + fr][kt*32 + kc*8];
                #pragma unroll
                for (int mt = 0; mt < 4; ++mt)
                    #pragma unroll
                    for (int jt = 0; jt < 2; ++jt)
                        acc2[mt][jt] = __builtin_amdgcn_mfma_f32_16x16x32_bf16(a4[mt], b2[jt], acc2[mt][jt], 0, 0, 0);
            }
            ushort* sb = states + ((((size_t)b * NCHUNK + c) * NHEADS + hh) * HEADDIM) * DSTATE;
            #pragma unroll
            for (int mt = 0; mt < 4; ++mt)
                #pragma unroll
                for (int jt = 0; jt < 2; ++jt)
                    #pragma unroll
                    for (int q = 0; q < 4; ++q) {
                        int p = mt*16 + (lane >> 4)*4 + q;
                        int n = w*32 + jt*16 + fr;
                        sb[(size_t)p * DSTATE + n] = f2bf(acc2[mt][jt][q]);
                    }
        }
        __syncthreads();
    }
}

// ------------------------------------- inter-chunk scan (bf16 states, f32 regs)
__global__ __launch_bounds__(256) void scan_k(ushort* __restrict__ states,
                                              const float* __restrict__ chunksum) {
    const int bid = blockIdx.x;
    const int pq = bid & 3, h = (bid >> 2) & 7, b = bid >> 5;
    const int tid = threadIdx.x;
    float pref[8];
    #pragma unroll
    for (int k = 0; k < 8; ++k) pref[k] = 0.f;
    for (int c = 0; c < NCHUNK; ++c) {
        ushort* base = states + (((size_t)b * NCHUNK + c) * NHEADS + h) * (HEADDIM * DSTATE)
                       + pq * 2048 + tid * 8;
        float dec = __expf(chunksum[((size_t)b * NCHUNK + c) * NHEADS + h]);
        uint4 v = *(const uint4*)base;
        const ushort* pv = (const ushort*)&v;
        ushort outv[8];
        #pragma unroll
        for (int j = 0; j < 8; ++j) {
            float cur = bf2f(pv[j]);
            outv[j] = f2bf(pref[j]);
            pref[j] = dec * pref[j] + cur;
        }
        *(uint4*)base = *(uint4*)outv;
    }
}

// ----- Y_off + gate + RMSNorm + fused out-proj (32-row blocks, XCD-chunked)
__global__ __launch_bounds__(256) void yoff_gate_k(const ushort* __restrict__ xbc,
                                                   const ushort* __restrict__ states,
                                                   const float* __restrict__ acsbuf,
                                                   const ushort* __restrict__ ybuf,
                                                   const ushort* __restrict__ zx,
                                                   const float* __restrict__ nw,
                                                   const ushort* __restrict__ WtB,
                                                   float* __restrict__ out) {
    const int wk = (blockIdx.x & 7) * 64 + (blockIdx.x >> 3);
    const int half = wk & 1, c = (wk >> 1) & 15, b = wk >> 5;
    const int row0 = b * SEQ + c * LCHUNK + half * 32;
    const int tid = threadIdx.x;
    const int lane = tid & 63, w = tid >> 6;
    const int fr = lane & 15, kc = lane >> 4;
    const int rw = (w & 1) * 16;           // wave row range (16 of 32)
    const int j0 = (w >> 1) * 2;           // wave col-frag pair
    __shared__ ushort Csh[32][SLDA];
    __shared__ ushort Ssh[64][SLDA];
    __shared__ ushort Ys[32][520];
    __shared__ float eah[32];

    #pragma unroll
    for (int it = 0; it < 2; ++it) {
        int idx = tid + it * 256;          // 512 grains: l(32) x ng(16)
        int l = idx >> 4, ng = idx & 15;
        *(uint4*)&Csh[l][ng * 8] =
            *(const uint4*)&xbc[(size_t)(row0 + l) * CONVDIM + DINNER + DSTATE + ng * 8];
    }
    for (int hl = 0; hl < NHEADS; ++hl) {
        __syncthreads();
        const ushort* sb = states + ((((size_t)b * NCHUNK + c) * NHEADS + hl) * HEADDIM) * DSTATE;
        #pragma unroll
        for (int it = 0; it < 4; ++it) {
            int idx = tid + it * 256;
            int p = idx >> 4, ng = idx & 15;
            *(uint4*)&Ssh[p][ng * 8] = *(const uint4*)&sb[(size_t)p * DSTATE + ng * 8];
        }
        if (tid < 32)
            eah[tid] = __expf(acsbuf[(((size_t)b * NCHUNK + c) * NHEADS + hl) * LCHUNK
                                     + half * 32 + tid]);
        __syncthreads();
        f32x4 acc[2];
        acc[0] = (f32x4)0.f; acc[1] = (f32x4)0.f;
        #pragma unroll
        for (int kt = 0; kt < 4; ++kt) {
            bf16x8 af = *(const bf16x8*)&Csh[rw + fr][kt*32 + kc*8];
            #pragma unroll
            for (int jj = 0; jj < 2; ++jj) {
                bf16x8 bfv = *(const bf16x8*)&Ssh[(j0+jj)*16 + fr][kt*32 + kc*8];
                acc[jj] = __builtin_amdgcn_mfma_f32_16x16x32_bf16(af, bfv, acc[jj], 0, 0, 0);
            }
        }
        #pragma unroll
        for (int jj = 0; jj < 2; ++jj)
            #pragma unroll
            for (int q = 0; q < 4; ++q) {
                int l = rw + (lane >> 4)*4 + q;
                int p = (j0+jj)*16 + fr;
                float val = bf2f(ybuf[(size_t)(row0 + l) * DINNER + hl * HEADDIM + p])
                            + acc[jj][q] * eah[l];
                Ys[l][hl * HEADDIM + p] = f2bf(val);
            }
    }
    __syncthreads();
    // gate + RMSNorm: wave w -> rows w*8 .. w*8+7; write g back into Ys (bf16)
    float nwv[8];
    #pragma unroll
    for (int j = 0; j < 8; ++j) nwv[j] = nw[lane * 8 + j];
    #pragma unroll
    for (int i = 0; i < 8; ++i) {
        int l = w * 8 + i;
        int row = row0 + l;
        uint4 zv = *(const uint4*)&zx[(size_t)row * ZXLD + lane * 8];
        const ushort* pz = (const ushort*)&zv;
        float g[8], ss = 0.f;
        #pragma unroll
        for (int j = 0; j < 8; ++j) {
            float y = bf2f(Ys[l][lane * 8 + j]);
            float z = bf2f(pz[j]);
            float sz = z / (1.f + __expf(-z));
            g[j] = y * sz;
            ss += g[j] * g[j];
        }
        #pragma unroll
        for (int off = 32; off; off >>= 1) ss += __shfl_xor(ss, off);
        float r = rsqrtf(ss / (float)DINNER + EPSV);
        ushort res[8];
        #pragma unroll
        for (int j = 0; j < 8; ++j) res[j] = f2bf(g[j] * r * nwv[j]);
        *(ushort4*)&Ys[l][lane * 8]     = *(ushort4*)&res[0];
        *(ushort4*)&Ys[l][lane * 8 + 4] = *(ushort4*)&res[4];
    }
    __syncthreads();
    // fused out-proj: out[32 x 256] = g(Ys, 32x512) @ WtB^T (WtB: [256 n][512 k])
    // wave w -> col-frags w*4 .. w*4+3, both row-frags. 16 k-steps.
    {
        const int cj0 = w * 4;
        f32x4 accO[2][4];
        #pragma unroll
        for (int ri = 0; ri < 2; ++ri)
            #pragma unroll
            for (int j = 0; j < 4; ++j) accO[ri][j] = (f32x4)0.f;
        for (int kt = 0; kt < 16; ++kt) {
            bf16x8 af[2], bfv[4];
            #pragma unroll
            for (int ri = 0; ri < 2; ++ri)
                af[ri] = *(const bf16x8*)&Ys[ri*16 + fr][kt*32 + kc*8];
            #pragma unroll
            for (int j = 0; j < 4; ++j) {
                int n = (cj0 + j) * 16 + fr;
                bfv[j] = *(const bf16x8*)&WtB[(size_t)n * DINNER + kt*32 + kc*8];
            }
            #pragma unroll
            for (int ri = 0; ri < 2; ++ri)
                #pragma unroll
                for (int j = 0; j < 4; ++j)
                    accO[ri][j] = __builtin_amdgcn_mfma_f32_16x16x32_bf16(af[ri], bfv[j], accO[ri][j], 0, 0, 0);
        }
        #pragma unroll
        for (int ri = 0; ri < 2; ++ri)
            #pragma unroll
            for (int j = 0; j < 4; ++j)
                #pragma unroll
                for (int q = 0; q < 4; ++q) {
                    int rr = row0 + ri*16 + (lane >> 4)*4 + q;
                    int cc = (cj0 + j)*16 + fr;
                    out[(size_t)rr * DMODEL + cc] = accO[ri][j][q];
                }
    }
}

// ---------------------------------------------------------------- launch
extern "C" void kernel_launch(void* const* d_in, const int* in_sizes, int n_in,
                              void* d_out, int out_size, void* d_ws, size_t ws_size,
                              hipStream_t stream) {
    const float* u       = (const float*)d_in[0];
    const float* W_in    = (const float*)d_in[1];
    const float* conv_w  = (const float*)d_in[2];
    const float* conv_b  = (const float*)d_in[3];
    const float* dt_bias = (const float*)d_in[4];
    const float* A_log   = (const float*)d_in[5];
    const float* Dp      = (const float*)d_in[6];
    const float* norm_w  = (const float*)d_in[7];
    const float* W_out   = (const float*)d_in[8];
    float* out = (float*)d_out;

    char* p = (char*)d_ws;
    ushort* zx       = (ushort*)p; p += (size_t)ROWS * ZXLD * sizeof(ushort);
    ushort* ybuf     = (ushort*)p; p += (size_t)ROWS * DINNER * sizeof(ushort);
    ushort* states   = (ushort*)p; p += (size_t)BATCHN * NCHUNK * NHEADS * HEADDIM * DSTATE * sizeof(ushort);
    ushort* xbc      = (ushort*)p; p += (size_t)ROWS * CONVDIM * sizeof(ushort);
    ushort* ubf      = (ushort*)p; p += (size_t)ROWS * DMODEL * sizeof(ushort);
    float*  dtb      = (float*)p;  p += (size_t)ROWS * NHEADS  * sizeof(float);
    float*  adtb     = (float*)p;  p += (size_t)ROWS * NHEADS  * sizeof(float);
    float*  chunksum = (float*)p;  p += (size_t)BATCHN * NCHUNK * NHEADS * sizeof(float);
    float*  acsbuf   = (float*)p;  p += (size_t)BATCHN * NCHUNK * NHEADS * LCHUNK * sizeof(float);
    ushort* WtA      = (ushort*)p; p += (size_t)ZXLD * DMODEL * sizeof(ushort);
    ushort* WtB      = (ushort*)p; p += (size_t)DMODEL * DINNER * sizeof(ushort);

    // 1. dt GEMV + u cast + weight transposes
    prep_k<<<960, 256, 0, stream>>>(u, W_in, W_out, dt_bias, A_log,
                                    ubf, dtb, adtb, WtA, WtB);
    // 2. in-proj -> bf16 zx
    gemm_bf16<<<(ZXLD/128)*(ROWS/128), 256, 0, stream>>>(
        ubf, WtA, zx, ROWS, ZXLD, DMODEL, ZXLD/128);
    // 3. depthwise conv + silu
    conv_silu_k<<<(ROWS/4)*96/256, 256, 0, stream>>>(zx, conv_w, conv_b, xbc);
    // 4. SSD chunk kernel
    ssd_mfma_k<<<512, 256, 0, stream>>>(
        xbc, dtb, adtb, Dp, ybuf, states, acsbuf, chunksum);
    // 5. inter-chunk scan
    scan_k<<<BATCHN*NHEADS*4, 256, 0, stream>>>(states, chunksum);
    // 6. Y_off + gate + RMSNorm + out-proj (fused)
    yoff_gate_k<<<512, 256, 0, stream>>>(
        xbc, states, acsbuf, ybuf, zx, norm_w, WtB, out);
}

// Round 17
// 117.954 us; speedup vs baseline: 1.0892x; 1.0217x over previous
//
#include <hip/hip_runtime.h>
#include <hip/hip_bf16.h>
#include <math.h>

#define BATCHN  16
#define SEQ     1024
#define DMODEL  256
#define DSTATE  128
#define HEADDIM 64
#define DINNER  512
#define NHEADS  8
#define CONVDIM 768
#define DINPROJ 1288
#define ZXLD    1280
#define KCONV   4
#define NCHUNK  16
#define LCHUNK  64
#define EPSV    1e-5f
#define ROWS    (BATCHN*SEQ)

typedef __attribute__((ext_vector_type(8))) __bf16 bf16x8;
typedef __attribute__((ext_vector_type(4))) float  f32x4;

__device__ inline ushort f2bf(float f) {
    union { float f; uint32_t u; } v; v.f = f;
    uint32_t r = v.u + 0x7fff + ((v.u >> 16) & 1);
    return (ushort)(r >> 16);
}
__device__ inline float bf2f(ushort u) {
    union { uint32_t u; float f; } v; v.u = ((uint32_t)u) << 16;
    return v.f;
}

// ---------- prep: dt GEMV + u->bf16 cast (blocks 0..511) | W transposes (512..959)
__global__ __launch_bounds__(256) void prep_k(const float* __restrict__ u,
                                              const float* __restrict__ W_in,
                                              const float* __restrict__ W_out,
                                              const float* __restrict__ dt_bias,
                                              const float* __restrict__ A_log,
                                              ushort* __restrict__ ubf,
                                              float* __restrict__ dtb,
                                              float* __restrict__ adtb,
                                              ushort* __restrict__ WtA,
                                              ushort* __restrict__ WtB) {
    __shared__ union {
        struct { float Uld[32][264]; float Ws[DMODEL][NHEADS]; } d;
        float Ts[32][33];
    } S;
    const int tid = threadIdx.x;
    if (blockIdx.x < 512) {
        #pragma unroll
        for (int j = 0; j < 8; ++j) {
            int idx = tid + j * 256;
            S.d.Ws[idx >> 3][idx & 7] = W_in[(size_t)(idx >> 3) * DINPROJ + 1280 + (idx & 7)];
        }
        const int row0 = blockIdx.x * 32;
        #pragma unroll
        for (int v = 0; v < 8; ++v) {
            int e = v * 1024 + tid * 4;
            int r = e >> 8, cc = e & 255;
            float4 x = *(const float4*)&u[(size_t)(row0 + r) * DMODEL + cc];
            *(float4*)&S.d.Uld[r][cc] = x;
            ushort t4[4];
            t4[0]=f2bf(x.x); t4[1]=f2bf(x.y); t4[2]=f2bf(x.z); t4[3]=f2bf(x.w);
            *(ushort4*)&ubf[(size_t)(row0 + r) * DMODEL + cc] = *(ushort4*)t4;
        }
        __syncthreads();
        const int row = tid >> 3, h = tid & 7;
        float acc = 0.f;
        #pragma unroll 8
        for (int k = 0; k < DMODEL; k += 4) {
            float4 uv = *(const float4*)&S.d.Uld[row][k];
            acc += uv.x * S.d.Ws[k][h] + uv.y * S.d.Ws[k+1][h]
                 + uv.z * S.d.Ws[k+2][h] + uv.w * S.d.Ws[k+3][h];
        }
        float v = acc + dt_bias[h];
        float dt = (v > 20.f) ? v : log1pf(__expf(v));
        dtb [(size_t)(row0 + row) * NHEADS + h] = dt;
        adtb[(size_t)(row0 + row) * NHEADS + h] = dt * (-__expf(A_log[h]));
    } else {
        int bid = blockIdx.x - 512;
        const float* src; ushort* dst; int K, ldsrc, nx;
        if (bid < 320) { src = W_in;  dst = WtA; K = DMODEL; ldsrc = DINPROJ; nx = 40; }
        else { bid -= 320; src = W_out; dst = WtB; K = DINNER; ldsrc = DMODEL; nx = 8; }
        const int n0 = (bid % nx) * 32, k0 = (bid / nx) * 32;
        const int tx = tid & 31, ty = tid >> 5;
        #pragma unroll
        for (int j = 0; j < 4; ++j) {
            int kl = ty * 4 + j;
            S.Ts[kl][tx] = src[(size_t)(k0 + kl) * ldsrc + n0 + tx];
        }
        __syncthreads();
        #pragma unroll
        for (int j = 0; j < 4; ++j) {
            int nl = ty * 4 + j;
            dst[(size_t)(n0 + nl) * K + k0 + tx] = f2bf(S.Ts[tx][nl]);
        }
    }
}

// ------------------------------------------------------- bf16 MFMA GEMM
// bf16 output, repacks the tile through LDS -> uint4 stores.
#define LDSW 72
#define TILEC 132
__global__ __launch_bounds__(256) void gemm_bf16(const ushort* __restrict__ A,
                                                 const ushort* __restrict__ Bt,
                                                 ushort* __restrict__ C,
                                                 int M, int N, int K, int nx) {
    __shared__ ushort LB[2 * 128 * LDSW];
    ushort* As = LB;
    ushort* Bs = LB + 128 * LDSW;
    const int tid  = threadIdx.x;
    const int nwg  = gridDim.x;
    const int work = (blockIdx.x & 7) * (nwg >> 3) + (blockIdx.x >> 3);
    const int m0 = (work / nx) * 128, n0 = (work % nx) * 128;
    const int wid = tid >> 6, lane = tid & 63;
    const int wr = wid >> 1, wc = wid & 1;
    const int r = tid >> 1, kq = tid & 1;
    const int fr = lane & 15, kc = lane >> 4;

    f32x4 acc[4][4];
    #pragma unroll
    for (int i = 0; i < 4; ++i)
        #pragma unroll
        for (int j = 0; j < 4; ++j) acc[i][j] = (f32x4)0.f;

    for (int kt = 0; kt < K; kt += 64) {
        const ushort* ap = &A [(size_t)(m0 + r) * K + kt + kq * 32];
        const ushort* bp = &Bt[(size_t)(n0 + r) * K + kt + kq * 32];
        #pragma unroll
        for (int v = 0; v < 4; ++v) {
            *(uint4*)&As[r * LDSW + kq * 32 + v * 8] = *(const uint4*)(ap + v * 8);
            *(uint4*)&Bs[r * LDSW + kq * 32 + v * 8] = *(const uint4*)(bp + v * 8);
        }
        __syncthreads();
        #pragma unroll
        for (int kk = 0; kk < 2; ++kk) {
            bf16x8 af[4], bfv[4];
            #pragma unroll
            for (int i = 0; i < 4; ++i) {
                af[i]  = *(const bf16x8*)&As[(wr * 64 + i * 16 + fr) * LDSW + kk * 32 + kc * 8];
                bfv[i] = *(const bf16x8*)&Bs[(wc * 64 + i * 16 + fr) * LDSW + kk * 32 + kc * 8];
            }
            #pragma unroll
            for (int i = 0; i < 4; ++i)
                #pragma unroll
                for (int j = 0; j < 4; ++j)
                    acc[i][j] = __builtin_amdgcn_mfma_f32_16x16x32_bf16(af[i], bfv[j], acc[i][j], 0, 0, 0);
        }
        __syncthreads();
    }
    ushort (*Tile)[TILEC] = (ushort (*)[TILEC])LB;
    #pragma unroll
    for (int i = 0; i < 4; ++i)
        #pragma unroll
        for (int j = 0; j < 4; ++j)
            #pragma unroll
            for (int q = 0; q < 4; ++q)
                Tile[wr * 64 + i * 16 + (lane >> 4) * 4 + q]
                    [wc * 64 + j * 16 + (lane & 15)] = f2bf(acc[i][j][q]);
    __syncthreads();
    #pragma unroll
    for (int it = 0; it < 8; ++it) {
        int idx = tid + it * 256;
        int rr = idx >> 4, g = idx & 15;
        *(uint4*)&C[(size_t)(m0 + rr) * N + n0 + g * 8] = *(uint4*)&Tile[rr][g * 8];
    }
}

// ------------------- depthwise conv + SiLU: LDS weights, 4 t-steps/thread
__global__ __launch_bounds__(256) void conv_silu_k(const ushort* __restrict__ zx,
                                                   const float* __restrict__ cw,
                                                   const float* __restrict__ cb,
                                                   ushort* __restrict__ out) {
    __shared__ float cws[KCONV][CONVDIM];
    __shared__ float cbs[CONVDIM];
    const int tid = threadIdx.x;
    #pragma unroll
    for (int it = 0; it < 3; ++it) {
        int i = tid + it * 256;
        cbs[i] = cb[i];
        #pragma unroll
        for (int k = 0; k < KCONV; ++k) cws[k][i] = cw[i * KCONV + k];
    }
    __syncthreads();

    const int idx = blockIdx.x * 256 + tid;
    const int cg = idx % 96, btq = idx / 96;
    const int c0 = cg * 8;
    const int bt0 = btq * 4;
    const int t0 = bt0 & (SEQ - 1);

    float wv[KCONV][8], bias[8];
    #pragma unroll
    for (int j = 0; j < 8; ++j) bias[j] = cbs[c0 + j];
    #pragma unroll
    for (int k = 0; k < KCONV; ++k) {
        float4 a = *(const float4*)&cws[k][c0];
        float4 b = *(const float4*)&cws[k][c0 + 4];
        wv[k][0] = a.x; wv[k][1] = a.y; wv[k][2] = a.z; wv[k][3] = a.w;
        wv[k][4] = b.x; wv[k][5] = b.y; wv[k][6] = b.z; wv[k][7] = b.w;
    }
    float xr[7][8];
    #pragma unroll
    for (int r = 0; r < 7; ++r) {
        int tt = t0 - 3 + r;
        if (tt >= 0) {
            uint4 v = *(const uint4*)&zx[(size_t)(bt0 - 3 + r) * ZXLD + DINNER + c0];
            const ushort* pv = (const ushort*)&v;
            #pragma unroll
            for (int j = 0; j < 8; ++j) xr[r][j] = bf2f(pv[j]);
        } else {
            #pragma unroll
            for (int j = 0; j < 8; ++j) xr[r][j] = 0.f;
        }
    }
    #pragma unroll
    for (int dt = 0; dt < 4; ++dt) {
        float acc[8];
        #pragma unroll
        for (int j = 0; j < 8; ++j) acc[j] = bias[j];
        #pragma unroll
        for (int k = 0; k < KCONV; ++k)
            #pragma unroll
            for (int j = 0; j < 8; ++j) acc[j] += xr[dt + k][j] * wv[k][j];
        ushort res[8];
        #pragma unroll
        for (int j = 0; j < 8; ++j)
            res[j] = f2bf(acc[j] / (1.f + __expf(-acc[j])));
        *(uint4*)&out[(size_t)(bt0 + dt) * CONVDIM + c0] = *(uint4*)res;
    }
}

// -------------------------------------------------- SSD MFMA kernel (XCD-swizzled)
#define SLDA 136
#define SLDB 72
__global__ __launch_bounds__(256) void ssd_mfma_k(const ushort* __restrict__ xbc,
                                                  const float* __restrict__ dtb,
                                                  const float* __restrict__ adtb,
                                                  const float* __restrict__ Dp,
                                                  ushort* __restrict__ ybuf,
                                                  ushort* __restrict__ states,
                                                  float* __restrict__ acsbuf,
                                                  float* __restrict__ chunksum) {
    const int wk = (blockIdx.x & 7) * 64 + (blockIdx.x >> 3);
    const int hgrp = wk & 1, c = (wk >> 1) & 15, b = wk >> 5;
    const int row0 = b * SEQ + c * LCHUNK;
    const int tid = threadIdx.x;
    const int lane = tid & 63, w = tid >> 6;
    const int fr = lane & 15, kc = lane >> 4;

    __shared__ union {
        struct { ushort Bs[64][SLDA]; ushort Cs[64][SLDA]; } p1;
        struct { ushort Ps[64][SLDB]; ushort Xt[64][SLDB]; ushort Xdt[64][SLDB]; } p2;
    } U;
    __shared__ ushort Btr[128][SLDB];
    __shared__ float acs4[4][64];
    __shared__ float dts[4][64];
    __shared__ float decs[4][64];

    {
        const int hh = hgrp * 4 + w;
        float v = adtb[(size_t)(row0 + lane) * NHEADS + hh];
        #pragma unroll
        for (int off = 1; off < 64; off <<= 1) {
            float t = __shfl_up(v, off);
            if (lane >= off) v += t;
        }
        acs4[w][lane] = v;
        float tot = __shfl(v, 63);
        decs[w][lane] = __expf(tot - v);
        acsbuf[(((size_t)b * NCHUNK + c) * NHEADS + hh) * LCHUNK + lane] = v;
        if (lane == 63) chunksum[((size_t)b * NCHUNK + c) * NHEADS + hh] = v;
        dts[w][lane] = dtb[(size_t)(row0 + lane) * NHEADS + hh];
    }
    for (int it = 0; it < 4; ++it) {
        int idx = tid + it * 256;
        int l = idx >> 4, ng = idx & 15;
        const ushort* rp = &xbc[(size_t)(row0 + l) * CONVDIM + DINNER];
        uint4 vb = *(const uint4*)(rp + ng * 8);
        *(uint4*)&U.p1.Bs[l][ng * 8] = vb;
        uint4 vc = *(const uint4*)(rp + DSTATE + ng * 8);
        *(uint4*)&U.p1.Cs[l][ng * 8] = vc;
        const ushort* pv = (const ushort*)&vb;
        #pragma unroll
        for (int j = 0; j < 8; ++j) Btr[ng * 8 + j][l] = pv[j];
    }
    __syncthreads();

    const int wr = w >> 1, wc = w & 1;
    f32x4 accG[2][2];
    #pragma unroll
    for (int i = 0; i < 2; ++i)
        #pragma unroll
        for (int j = 0; j < 2; ++j) accG[i][j] = (f32x4)0.f;
    #pragma unroll
    for (int kt = 0; kt < 4; ++kt) {
        bf16x8 af[2], bfv[2];
        #pragma unroll
        for (int i = 0; i < 2; ++i) af[i]  = *(const bf16x8*)&U.p1.Cs[wr*32 + i*16 + fr][kt*32 + kc*8];
        #pragma unroll
        for (int j = 0; j < 2; ++j) bfv[j] = *(const bf16x8*)&U.p1.Bs[wc*32 + j*16 + fr][kt*32 + kc*8];
        #pragma unroll
        for (int i = 0; i < 2; ++i)
            #pragma unroll
            for (int j = 0; j < 2; ++j)
                accG[i][j] = __builtin_amdgcn_mfma_f32_16x16x32_bf16(af[i], bfv[j], accG[i][j], 0, 0, 0);
    }
    __syncthreads();

    for (int hl = 0; hl < 4; ++hl) {
        const int hh = hgrp * 4 + hl;
        {
            const int p = lane;
            ushort xt[16], xdt[16];
            #pragma unroll
            for (int j = 0; j < 16; ++j) {
                int l = w * 16 + j;
                float xv = bf2f(xbc[(size_t)(row0 + l) * CONVDIM + hh * HEADDIM + p])
                           * dts[hl][l];
                xt[j]  = f2bf(xv);
                xdt[j] = f2bf(xv * decs[hl][l]);
            }
            #pragma unroll
            for (int v = 0; v < 4; ++v) {
                *(ushort4*)&U.p2.Xt [p][w*16 + v*4] = *(ushort4*)&xt[v*4];
                *(ushort4*)&U.p2.Xdt[p][w*16 + v*4] = *(ushort4*)&xdt[v*4];
            }
        }
        #pragma unroll
        for (int i = 0; i < 2; ++i)
            #pragma unroll
            for (int j = 0; j < 2; ++j)
                #pragma unroll
                for (int q = 0; q < 4; ++q) {
                    int l = wr*32 + i*16 + (lane >> 4)*4 + q;
                    int s = wc*32 + j*16 + fr;
                    float v = 0.f;
                    if (s < l)       v = accG[i][j][q] * __expf(acs4[hl][l] - acs4[hl][s]);
                    else if (s == l) v = accG[i][j][q] + Dp[hh] / dts[hl][l];
                    U.p2.Ps[l][s] = f2bf(v);
                }
        __syncthreads();
        {
            f32x4 acc[4];
            #pragma unroll
            for (int j = 0; j < 4; ++j) acc[j] = (f32x4)0.f;
            #pragma unroll
            for (int kt = 0; kt < 2; ++kt) {
                bf16x8 af = *(const bf16x8*)&U.p2.Ps[w*16 + fr][kt*32 + kc*8];
                #pragma unroll
                for (int j = 0; j < 4; ++j) {
                    bf16x8 bfv = *(const bf16x8*)&U.p2.Xt[j*16 + fr][kt*32 + kc*8];
                    acc[j] = __builtin_amdgcn_mfma_f32_16x16x32_bf16(af, bfv, acc[j], 0, 0, 0);
                }
            }
            #pragma unroll
            for (int j = 0; j < 4; ++j)
                #pragma unroll
                for (int q = 0; q < 4; ++q) {
                    int l = w*16 + (lane >> 4)*4 + q;
                    int p = j*16 + fr;
                    ybuf[(size_t)(row0 + l) * DINNER + hh * HEADDIM + p] = f2bf(acc[j][q]);
                }
        }
        {
            f32x4 acc2[4][2];
            #pragma unroll
            for (int mt = 0; mt < 4; ++mt)
                #pragma unroll
                for (int jt = 0; jt < 2; ++jt) acc2[mt][jt] = (f32x4)0.f;
            #pragma unroll
            for (int kt = 0; kt < 2; ++kt) {
                bf16x8 a4[4], b2[2];
                #pragma unroll
                for (int mt = 0; mt < 4; ++mt) a4[mt] = *(const bf16x8*)&U.p2.Xdt[mt*16 + fr][kt*32 + kc*8];
                #pragma unroll
                for (int jt = 0; jt < 2; ++jt) b2[jt] = *(const bf16x8*)&Btr[w*32 + jt*16 + fr][kt*32 + kc*8];
                #pragma unroll
                for (int mt = 0; mt < 4; ++mt)
                    #pragma unroll
                    for (int jt = 0; jt < 2; ++jt)
                        acc2[mt][jt] = __builtin_amdgcn_mfma_f32_16x16x32_bf16(a4[mt], b2[jt], acc2[mt][jt], 0, 0, 0);
            }
            ushort* sb = states + ((((size_t)b * NCHUNK + c) * NHEADS + hh) * HEADDIM) * DSTATE;
            #pragma unroll
            for (int mt = 0; mt < 4; ++mt)
                #pragma unroll
                for (int jt = 0; jt < 2; ++jt)
                    #pragma unroll
                    for (int q = 0; q < 4; ++q) {
                        int p = mt*16 + (lane >> 4)*4 + q;
                        int n = w*32 + jt*16 + fr;
                        sb[(size_t)p * DSTATE + n] = f2bf(acc2[mt][jt][q]);
                    }
        }
        __syncthreads();
    }
}

// ------------------------------------- inter-chunk scan (bf16 states, f32 regs)
__global__ __launch_bounds__(256) void scan_k(ushort* __restrict__ states,
                                              const float* __restrict__ chunksum) {
    const int bid = blockIdx.x;
    const int pq = bid & 3, h = (bid >> 2) & 7, b = bid >> 5;
    const int tid = threadIdx.x;
    float pref[8];
    #pragma unroll
    for (int k = 0; k < 8; ++k) pref[k] = 0.f;
    for (int c = 0; c < NCHUNK; ++c) {
        ushort* base = states + (((size_t)b * NCHUNK + c) * NHEADS + h) * (HEADDIM * DSTATE)
                       + pq * 2048 + tid * 8;
        float dec = __expf(chunksum[((size_t)b * NCHUNK + c) * NHEADS + h]);
        uint4 v = *(const uint4*)base;
        const ushort* pv = (const ushort*)&v;
        ushort outv[8];
        #pragma unroll
        for (int j = 0; j < 8; ++j) {
            float cur = bf2f(pv[j]);
            outv[j] = f2bf(pref[j]);
            pref[j] = dec * pref[j] + cur;
        }
        *(uint4*)base = *(uint4*)outv;
    }
}

// ----- Y_off + gate + RMSNorm + fused out-proj (32-row blocks, XCD-chunked)
// Heads processed in PAIRS: double Ssh buffer, 8 barrier phases instead of 16.
__global__ __launch_bounds__(256) void yoff_gate_k(const ushort* __restrict__ xbc,
                                                   const ushort* __restrict__ states,
                                                   const float* __restrict__ acsbuf,
                                                   const ushort* __restrict__ ybuf,
                                                   const ushort* __restrict__ zx,
                                                   const float* __restrict__ nw,
                                                   const ushort* __restrict__ WtB,
                                                   float* __restrict__ out) {
    const int wk = (blockIdx.x & 7) * 64 + (blockIdx.x >> 3);
    const int half = wk & 1, c = (wk >> 1) & 15, b = wk >> 5;
    const int row0 = b * SEQ + c * LCHUNK + half * 32;
    const int tid = threadIdx.x;
    const int lane = tid & 63, w = tid >> 6;
    const int fr = lane & 15, kc = lane >> 4;
    const int rw = (w & 1) * 16;           // wave row range (16 of 32)
    const int j0 = (w >> 1) * 2;           // wave col-frag pair
    __shared__ ushort Csh[32][SLDA];
    __shared__ ushort Ssh[2][64][SLDA];
    __shared__ ushort Ys[32][520];
    __shared__ float eah[2][32];

    #pragma unroll
    for (int it = 0; it < 2; ++it) {
        int idx = tid + it * 256;          // 512 grains: l(32) x ng(16)
        int l = idx >> 4, ng = idx & 15;
        *(uint4*)&Csh[l][ng * 8] =
            *(const uint4*)&xbc[(size_t)(row0 + l) * CONVDIM + DINNER + DSTATE + ng * 8];
    }
    for (int hp = 0; hp < 4; ++hp) {       // head pairs 2hp, 2hp+1
        __syncthreads();                   // prev pair's MFMAs done (covers Csh on hp=0)
        #pragma unroll
        for (int hh2 = 0; hh2 < 2; ++hh2) {
            const int hl = hp * 2 + hh2;
            const ushort* sb = states + ((((size_t)b * NCHUNK + c) * NHEADS + hl) * HEADDIM) * DSTATE;
            #pragma unroll
            for (int it = 0; it < 4; ++it) {
                int idx = tid + it * 256;
                int p = idx >> 4, ng = idx & 15;
                *(uint4*)&Ssh[hh2][p][ng * 8] = *(const uint4*)&sb[(size_t)p * DSTATE + ng * 8];
            }
        }
        if (tid < 64) {
            int hh2 = tid >> 5, t = tid & 31;
            eah[hh2][t] = __expf(acsbuf[(((size_t)b * NCHUNK + c) * NHEADS + hp*2 + hh2) * LCHUNK
                                        + half * 32 + t]);
        }
        __syncthreads();
        #pragma unroll
        for (int hh2 = 0; hh2 < 2; ++hh2) {
            const int hl = hp * 2 + hh2;
            f32x4 acc[2];
            acc[0] = (f32x4)0.f; acc[1] = (f32x4)0.f;
            #pragma unroll
            for (int kt = 0; kt < 4; ++kt) {
                bf16x8 af = *(const bf16x8*)&Csh[rw + fr][kt*32 + kc*8];
                #pragma unroll
                for (int jj = 0; jj < 2; ++jj) {
                    bf16x8 bfv = *(const bf16x8*)&Ssh[hh2][(j0+jj)*16 + fr][kt*32 + kc*8];
                    acc[jj] = __builtin_amdgcn_mfma_f32_16x16x32_bf16(af, bfv, acc[jj], 0, 0, 0);
                }
            }
            #pragma unroll
            for (int jj = 0; jj < 2; ++jj)
                #pragma unroll
                for (int q = 0; q < 4; ++q) {
                    int l = rw + (lane >> 4)*4 + q;
                    int p = (j0+jj)*16 + fr;
                    float val = bf2f(ybuf[(size_t)(row0 + l) * DINNER + hl * HEADDIM + p])
                                + acc[jj][q] * eah[hh2][l];
                    Ys[l][hl * HEADDIM + p] = f2bf(val);
                }
        }
    }
    __syncthreads();
    // gate + RMSNorm: wave w -> rows w*8 .. w*8+7; write g back into Ys (bf16)
    float nwv[8];
    #pragma unroll
    for (int j = 0; j < 8; ++j) nwv[j] = nw[lane * 8 + j];
    #pragma unroll
    for (int i = 0; i < 8; ++i) {
        int l = w * 8 + i;
        int row = row0 + l;
        uint4 zv = *(const uint4*)&zx[(size_t)row * ZXLD + lane * 8];
        const ushort* pz = (const ushort*)&zv;
        float g[8], ss = 0.f;
        #pragma unroll
        for (int j = 0; j < 8; ++j) {
            float y = bf2f(Ys[l][lane * 8 + j]);
            float z = bf2f(pz[j]);
            float sz = z / (1.f + __expf(-z));
            g[j] = y * sz;
            ss += g[j] * g[j];
        }
        #pragma unroll
        for (int off = 32; off; off >>= 1) ss += __shfl_xor(ss, off);
        float r = rsqrtf(ss / (float)DINNER + EPSV);
        ushort res[8];
        #pragma unroll
        for (int j = 0; j < 8; ++j) res[j] = f2bf(g[j] * r * nwv[j]);
        *(ushort4*)&Ys[l][lane * 8]     = *(ushort4*)&res[0];
        *(ushort4*)&Ys[l][lane * 8 + 4] = *(ushort4*)&res[4];
    }
    __syncthreads();
    // fused out-proj: out[32 x 256] = g(Ys, 32x512) @ WtB^T (WtB: [256 n][512 k])
    {
        const int cj0 = w * 4;
        f32x4 accO[2][4];
        #pragma unroll
        for (int ri = 0; ri < 2; ++ri)
            #pragma unroll
            for (int j = 0; j < 4; ++j) accO[ri][j] = (f32x4)0.f;
        for (int kt = 0; kt < 16; ++kt) {
            bf16x8 af[2], bfv[4];
            #pragma unroll
            for (int ri = 0; ri < 2; ++ri)
                af[ri] = *(const bf16x8*)&Ys[ri*16 + fr][kt*32 + kc*8];
            #pragma unroll
            for (int j = 0; j < 4; ++j) {
                int n = (cj0 + j) * 16 + fr;
                bfv[j] = *(const bf16x8*)&WtB[(size_t)n * DINNER + kt*32 + kc*8];
            }
            #pragma unroll
            for (int ri = 0; ri < 2; ++ri)
                #pragma unroll
                for (int j = 0; j < 4; ++j)
                    accO[ri][j] = __builtin_amdgcn_mfma_f32_16x16x32_bf16(af[ri], bfv[j], accO[ri][j], 0, 0, 0);
        }
        #pragma unroll
        for (int ri = 0; ri < 2; ++ri)
            #pragma unroll
            for (int j = 0; j < 4; ++j)
                #pragma unroll
                for (int q = 0; q < 4; ++q) {
                    int rr = row0 + ri*16 + (lane >> 4)*4 + q;
                    int cc = (cj0 + j)*16 + fr;
                    out[(size_t)rr * DMODEL + cc] = accO[ri][j][q];
                }
    }
}

// ---------------------------------------------------------------- launch
extern "C" void kernel_launch(void* const* d_in, const int* in_sizes, int n_in,
                              void* d_out, int out_size, void* d_ws, size_t ws_size,
                              hipStream_t stream) {
    const float* u       = (const float*)d_in[0];
    const float* W_in    = (const float*)d_in[1];
    const float* conv_w  = (const float*)d_in[2];
    const float* conv_b  = (const float*)d_in[3];
    const float* dt_bias = (const float*)d_in[4];
    const float* A_log   = (const float*)d_in[5];
    const float* Dp      = (const float*)d_in[6];
    const float* norm_w  = (const float*)d_in[7];
    const float* W_out   = (const float*)d_in[8];
    float* out = (float*)d_out;

    char* p = (char*)d_ws;
    ushort* zx       = (ushort*)p; p += (size_t)ROWS * ZXLD * sizeof(ushort);
    ushort* ybuf     = (ushort*)p; p += (size_t)ROWS * DINNER * sizeof(ushort);
    ushort* states   = (ushort*)p; p += (size_t)BATCHN * NCHUNK * NHEADS * HEADDIM * DSTATE * sizeof(ushort);
    ushort* xbc      = (ushort*)p; p += (size_t)ROWS * CONVDIM * sizeof(ushort);
    ushort* ubf      = (ushort*)p; p += (size_t)ROWS * DMODEL * sizeof(ushort);
    float*  dtb      = (float*)p;  p += (size_t)ROWS * NHEADS  * sizeof(float);
    float*  adtb     = (float*)p;  p += (size_t)ROWS * NHEADS  * sizeof(float);
    float*  chunksum = (float*)p;  p += (size_t)BATCHN * NCHUNK * NHEADS * sizeof(float);
    float*  acsbuf   = (float*)p;  p += (size_t)BATCHN * NCHUNK * NHEADS * LCHUNK * sizeof(float);
    ushort* WtA      = (ushort*)p; p += (size_t)ZXLD * DMODEL * sizeof(ushort);
    ushort* WtB      = (ushort*)p; p += (size_t)DMODEL * DINNER * sizeof(ushort);

    prep_k<<<960, 256, 0, stream>>>(u, W_in, W_out, dt_bias, A_log,
                                    ubf, dtb, adtb, WtA, WtB);
    gemm_bf16<<<(ZXLD/128)*(ROWS/128), 256, 0, stream>>>(
        ubf, WtA, zx, ROWS, ZXLD, DMODEL, ZXLD/128);
    conv_silu_k<<<(ROWS/4)*96/256, 256, 0, stream>>>(zx, conv_w, conv_b, xbc);
    ssd_mfma_k<<<512, 256, 0, stream>>>(
        xbc, dtb, adtb, Dp, ybuf, states, acsbuf, chunksum);
    scan_k<<<BATCHN*NHEADS*4, 256, 0, stream>>>(states, chunksum);
    yoff_gate_k<<<512, 256, 0, stream>>>(
        xbc, states, acsbuf, ybuf, zx, norm_w, WtB, out);
}

// Round 18
// 117.441 us; speedup vs baseline: 1.0940x; 1.0044x over previous
//
#include <hip/hip_runtime.h>
#include <hip/hip_bf16.h>
#include <math.h>

#define BATCHN  16
#define SEQ     1024
#define DMODEL  256
#define DSTATE  128
#define HEADDIM 64
#define DINNER  512
#define NHEADS  8
#define CONVDIM 768
#define DINPROJ 1288
#define ZXLD    1280
#define KCONV   4
#define NCHUNK  16
#define LCHUNK  64
#define EPSV    1e-5f
#define ROWS    (BATCHN*SEQ)

typedef __attribute__((ext_vector_type(8))) __bf16 bf16x8;
typedef __attribute__((ext_vector_type(4))) float  f32x4;

__device__ inline ushort f2bf(float f) {
    union { float f; uint32_t u; } v; v.f = f;
    uint32_t r = v.u + 0x7fff + ((v.u >> 16) & 1);
    return (ushort)(r >> 16);
}
__device__ inline float bf2f(ushort u) {
    union { uint32_t u; float f; } v; v.u = ((uint32_t)u) << 16;
    return v.f;
}

// ---------- prep: dt GEMV + u->bf16 cast (blocks 0..511) | W transposes (512..959)
__global__ __launch_bounds__(256) void prep_k(const float* __restrict__ u,
                                              const float* __restrict__ W_in,
                                              const float* __restrict__ W_out,
                                              const float* __restrict__ dt_bias,
                                              const float* __restrict__ A_log,
                                              ushort* __restrict__ ubf,
                                              float* __restrict__ dtb,
                                              float* __restrict__ adtb,
                                              ushort* __restrict__ WtA,
                                              ushort* __restrict__ WtB) {
    __shared__ union {
        struct { float Uld[32][264]; float Ws[DMODEL][NHEADS]; } d;
        float Ts[32][33];
    } S;
    const int tid = threadIdx.x;
    if (blockIdx.x < 512) {
        #pragma unroll
        for (int j = 0; j < 8; ++j) {
            int idx = tid + j * 256;
            S.d.Ws[idx >> 3][idx & 7] = W_in[(size_t)(idx >> 3) * DINPROJ + 1280 + (idx & 7)];
        }
        const int row0 = blockIdx.x * 32;
        #pragma unroll
        for (int v = 0; v < 8; ++v) {
            int e = v * 1024 + tid * 4;
            int r = e >> 8, cc = e & 255;
            float4 x = *(const float4*)&u[(size_t)(row0 + r) * DMODEL + cc];
            *(float4*)&S.d.Uld[r][cc] = x;
            ushort t4[4];
            t4[0]=f2bf(x.x); t4[1]=f2bf(x.y); t4[2]=f2bf(x.z); t4[3]=f2bf(x.w);
            *(ushort4*)&ubf[(size_t)(row0 + r) * DMODEL + cc] = *(ushort4*)t4;
        }
        __syncthreads();
        const int row = tid >> 3, h = tid & 7;
        float acc = 0.f;
        #pragma unroll 8
        for (int k = 0; k < DMODEL; k += 4) {
            float4 uv = *(const float4*)&S.d.Uld[row][k];
            acc += uv.x * S.d.Ws[k][h] + uv.y * S.d.Ws[k+1][h]
                 + uv.z * S.d.Ws[k+2][h] + uv.w * S.d.Ws[k+3][h];
        }
        float v = acc + dt_bias[h];
        float dt = (v > 20.f) ? v : log1pf(__expf(v));
        dtb [(size_t)(row0 + row) * NHEADS + h] = dt;
        adtb[(size_t)(row0 + row) * NHEADS + h] = dt * (-__expf(A_log[h]));
    } else {
        int bid = blockIdx.x - 512;
        const float* src; ushort* dst; int K, ldsrc, nx;
        if (bid < 320) { src = W_in;  dst = WtA; K = DMODEL; ldsrc = DINPROJ; nx = 40; }
        else { bid -= 320; src = W_out; dst = WtB; K = DINNER; ldsrc = DMODEL; nx = 8; }
        const int n0 = (bid % nx) * 32, k0 = (bid / nx) * 32;
        const int tx = tid & 31, ty = tid >> 5;
        #pragma unroll
        for (int j = 0; j < 4; ++j) {
            int kl = ty * 4 + j;
            S.Ts[kl][tx] = src[(size_t)(k0 + kl) * ldsrc + n0 + tx];
        }
        __syncthreads();
        #pragma unroll
        for (int j = 0; j < 4; ++j) {
            int nl = ty * 4 + j;
            dst[(size_t)(n0 + nl) * K + k0 + tx] = f2bf(S.Ts[tx][nl]);
        }
    }
}

// ------------------------------------------------------- bf16 MFMA GEMM
// bf16 output, repacks the tile through LDS -> uint4 stores.
#define LDSW 72
#define TILEC 132
__global__ __launch_bounds__(256) void gemm_bf16(const ushort* __restrict__ A,
                                                 const ushort* __restrict__ Bt,
                                                 ushort* __restrict__ C,
                                                 int M, int N, int K, int nx) {
    __shared__ ushort LB[2 * 128 * LDSW];
    ushort* As = LB;
    ushort* Bs = LB + 128 * LDSW;
    const int tid  = threadIdx.x;
    const int nwg  = gridDim.x;
    const int work = (blockIdx.x & 7) * (nwg >> 3) + (blockIdx.x >> 3);
    const int m0 = (work / nx) * 128, n0 = (work % nx) * 128;
    const int wid = tid >> 6, lane = tid & 63;
    const int wr = wid >> 1, wc = wid & 1;
    const int r = tid >> 1, kq = tid & 1;
    const int fr = lane & 15, kc = lane >> 4;

    f32x4 acc[4][4];
    #pragma unroll
    for (int i = 0; i < 4; ++i)
        #pragma unroll
        for (int j = 0; j < 4; ++j) acc[i][j] = (f32x4)0.f;

    for (int kt = 0; kt < K; kt += 64) {
        const ushort* ap = &A [(size_t)(m0 + r) * K + kt + kq * 32];
        const ushort* bp = &Bt[(size_t)(n0 + r) * K + kt + kq * 32];
        #pragma unroll
        for (int v = 0; v < 4; ++v) {
            *(uint4*)&As[r * LDSW + kq * 32 + v * 8] = *(const uint4*)(ap + v * 8);
            *(uint4*)&Bs[r * LDSW + kq * 32 + v * 8] = *(const uint4*)(bp + v * 8);
        }
        __syncthreads();
        #pragma unroll
        for (int kk = 0; kk < 2; ++kk) {
            bf16x8 af[4], bfv[4];
            #pragma unroll
            for (int i = 0; i < 4; ++i) {
                af[i]  = *(const bf16x8*)&As[(wr * 64 + i * 16 + fr) * LDSW + kk * 32 + kc * 8];
                bfv[i] = *(const bf16x8*)&Bs[(wc * 64 + i * 16 + fr) * LDSW + kk * 32 + kc * 8];
            }
            #pragma unroll
            for (int i = 0; i < 4; ++i)
                #pragma unroll
                for (int j = 0; j < 4; ++j)
                    acc[i][j] = __builtin_amdgcn_mfma_f32_16x16x32_bf16(af[i], bfv[j], acc[i][j], 0, 0, 0);
        }
        __syncthreads();
    }
    ushort (*Tile)[TILEC] = (ushort (*)[TILEC])LB;
    #pragma unroll
    for (int i = 0; i < 4; ++i)
        #pragma unroll
        for (int j = 0; j < 4; ++j)
            #pragma unroll
            for (int q = 0; q < 4; ++q)
                Tile[wr * 64 + i * 16 + (lane >> 4) * 4 + q]
                    [wc * 64 + j * 16 + (lane & 15)] = f2bf(acc[i][j][q]);
    __syncthreads();
    #pragma unroll
    for (int it = 0; it < 8; ++it) {
        int idx = tid + it * 256;
        int rr = idx >> 4, g = idx & 15;
        *(uint4*)&C[(size_t)(m0 + rr) * N + n0 + g * 8] = *(uint4*)&Tile[rr][g * 8];
    }
}

// ------------------- depthwise conv + SiLU: LDS weights, 4 t-steps/thread
__global__ __launch_bounds__(256) void conv_silu_k(const ushort* __restrict__ zx,
                                                   const float* __restrict__ cw,
                                                   const float* __restrict__ cb,
                                                   ushort* __restrict__ out) {
    __shared__ float cws[KCONV][CONVDIM];
    __shared__ float cbs[CONVDIM];
    const int tid = threadIdx.x;
    #pragma unroll
    for (int it = 0; it < 3; ++it) {
        int i = tid + it * 256;
        cbs[i] = cb[i];
        #pragma unroll
        for (int k = 0; k < KCONV; ++k) cws[k][i] = cw[i * KCONV + k];
    }
    __syncthreads();

    const int idx = blockIdx.x * 256 + tid;
    const int cg = idx % 96, btq = idx / 96;
    const int c0 = cg * 8;
    const int bt0 = btq * 4;
    const int t0 = bt0 & (SEQ - 1);

    float wv[KCONV][8], bias[8];
    #pragma unroll
    for (int j = 0; j < 8; ++j) bias[j] = cbs[c0 + j];
    #pragma unroll
    for (int k = 0; k < KCONV; ++k) {
        float4 a = *(const float4*)&cws[k][c0];
        float4 b = *(const float4*)&cws[k][c0 + 4];
        wv[k][0] = a.x; wv[k][1] = a.y; wv[k][2] = a.z; wv[k][3] = a.w;
        wv[k][4] = b.x; wv[k][5] = b.y; wv[k][6] = b.z; wv[k][7] = b.w;
    }
    float xr[7][8];
    #pragma unroll
    for (int r = 0; r < 7; ++r) {
        int tt = t0 - 3 + r;
        if (tt >= 0) {
            uint4 v = *(const uint4*)&zx[(size_t)(bt0 - 3 + r) * ZXLD + DINNER + c0];
            const ushort* pv = (const ushort*)&v;
            #pragma unroll
            for (int j = 0; j < 8; ++j) xr[r][j] = bf2f(pv[j]);
        } else {
            #pragma unroll
            for (int j = 0; j < 8; ++j) xr[r][j] = 0.f;
        }
    }
    #pragma unroll
    for (int dt = 0; dt < 4; ++dt) {
        float acc[8];
        #pragma unroll
        for (int j = 0; j < 8; ++j) acc[j] = bias[j];
        #pragma unroll
        for (int k = 0; k < KCONV; ++k)
            #pragma unroll
            for (int j = 0; j < 8; ++j) acc[j] += xr[dt + k][j] * wv[k][j];
        ushort res[8];
        #pragma unroll
        for (int j = 0; j < 8; ++j)
            res[j] = f2bf(acc[j] / (1.f + __expf(-acc[j])));
        *(uint4*)&out[(size_t)(bt0 + dt) * CONVDIM + c0] = *(uint4*)res;
    }
}

// ------------- SSD MFMA kernel (XCD-swizzled, head-pair phasing)
#define SLDA 136
#define SLDB 72
__global__ __launch_bounds__(256) void ssd_mfma_k(const ushort* __restrict__ xbc,
                                                  const float* __restrict__ dtb,
                                                  const float* __restrict__ adtb,
                                                  const float* __restrict__ Dp,
                                                  ushort* __restrict__ ybuf,
                                                  ushort* __restrict__ states,
                                                  float* __restrict__ acsbuf,
                                                  float* __restrict__ chunksum) {
    const int wk = (blockIdx.x & 7) * 64 + (blockIdx.x >> 3);
    const int hgrp = wk & 1, c = (wk >> 1) & 15, b = wk >> 5;
    const int row0 = b * SEQ + c * LCHUNK;
    const int tid = threadIdx.x;
    const int lane = tid & 63, w = tid >> 6;
    const int fr = lane & 15, kc = lane >> 4;

    __shared__ union {
        struct { ushort Bs[64][SLDA]; ushort Cs[64][SLDA]; } p1;
        struct { ushort Ps[2][64][SLDB]; ushort Xt[2][64][SLDB]; ushort Xdt[2][64][SLDB]; } p2;
    } U;
    __shared__ ushort Btr[128][SLDB];
    __shared__ float acs4[4][64];
    __shared__ float dts[4][64];
    __shared__ float decs[4][64];

    {
        const int hh = hgrp * 4 + w;
        float v = adtb[(size_t)(row0 + lane) * NHEADS + hh];
        #pragma unroll
        for (int off = 1; off < 64; off <<= 1) {
            float t = __shfl_up(v, off);
            if (lane >= off) v += t;
        }
        acs4[w][lane] = v;
        float tot = __shfl(v, 63);
        decs[w][lane] = __expf(tot - v);
        acsbuf[(((size_t)b * NCHUNK + c) * NHEADS + hh) * LCHUNK + lane] = v;
        if (lane == 63) chunksum[((size_t)b * NCHUNK + c) * NHEADS + hh] = v;
        dts[w][lane] = dtb[(size_t)(row0 + lane) * NHEADS + hh];
    }
    for (int it = 0; it < 4; ++it) {
        int idx = tid + it * 256;
        int l = idx >> 4, ng = idx & 15;
        const ushort* rp = &xbc[(size_t)(row0 + l) * CONVDIM + DINNER];
        uint4 vb = *(const uint4*)(rp + ng * 8);
        *(uint4*)&U.p1.Bs[l][ng * 8] = vb;
        uint4 vc = *(const uint4*)(rp + DSTATE + ng * 8);
        *(uint4*)&U.p1.Cs[l][ng * 8] = vc;
        const ushort* pv = (const ushort*)&vb;
        #pragma unroll
        for (int j = 0; j < 8; ++j) Btr[ng * 8 + j][l] = pv[j];
    }
    __syncthreads();

    const int wr = w >> 1, wc = w & 1;
    f32x4 accG[2][2];
    #pragma unroll
    for (int i = 0; i < 2; ++i)
        #pragma unroll
        for (int j = 0; j < 2; ++j) accG[i][j] = (f32x4)0.f;
    #pragma unroll
    for (int kt = 0; kt < 4; ++kt) {
        bf16x8 af[2], bfv[2];
        #pragma unroll
        for (int i = 0; i < 2; ++i) af[i]  = *(const bf16x8*)&U.p1.Cs[wr*32 + i*16 + fr][kt*32 + kc*8];
        #pragma unroll
        for (int j = 0; j < 2; ++j) bfv[j] = *(const bf16x8*)&U.p1.Bs[wc*32 + j*16 + fr][kt*32 + kc*8];
        #pragma unroll
        for (int i = 0; i < 2; ++i)
            #pragma unroll
            for (int j = 0; j < 2; ++j)
                accG[i][j] = __builtin_amdgcn_mfma_f32_16x16x32_bf16(af[i], bfv[j], accG[i][j], 0, 0, 0);
    }
    __syncthreads();   // G reads of p1 done; p2 overlay safe

    for (int hp = 0; hp < 2; ++hp) {       // head pairs within this hgrp
        // ---- build Xt/Xdt/Ps for both heads of the pair
        #pragma unroll
        for (int hh2 = 0; hh2 < 2; ++hh2) {
            const int hl = hp * 2 + hh2;
            const int hh = hgrp * 4 + hl;
            {
                const int p = lane;
                ushort xt[16], xdt[16];
                #pragma unroll
                for (int j = 0; j < 16; ++j) {
                    int l = w * 16 + j;
                    float xv = bf2f(xbc[(size_t)(row0 + l) * CONVDIM + hh * HEADDIM + p])
                               * dts[hl][l];
                    xt[j]  = f2bf(xv);
                    xdt[j] = f2bf(xv * decs[hl][l]);
                }
                #pragma unroll
                for (int v = 0; v < 4; ++v) {
                    *(ushort4*)&U.p2.Xt [hh2][p][w*16 + v*4] = *(ushort4*)&xt[v*4];
                    *(ushort4*)&U.p2.Xdt[hh2][p][w*16 + v*4] = *(ushort4*)&xdt[v*4];
                }
            }
            #pragma unroll
            for (int i = 0; i < 2; ++i)
                #pragma unroll
                for (int j = 0; j < 2; ++j)
                    #pragma unroll
                    for (int q = 0; q < 4; ++q) {
                        int l = wr*32 + i*16 + (lane >> 4)*4 + q;
                        int s = wc*32 + j*16 + fr;
                        float v = 0.f;
                        if (s < l)       v = accG[i][j][q] * __expf(acs4[hl][l] - acs4[hl][s]);
                        else if (s == l) v = accG[i][j][q] + Dp[hgrp*4 + hl] / dts[hl][l];
                        U.p2.Ps[hh2][l][s] = f2bf(v);
                    }
        }
        __syncthreads();
        // ---- compute Y + S for both heads
        #pragma unroll
        for (int hh2 = 0; hh2 < 2; ++hh2) {
            const int hl = hp * 2 + hh2;
            const int hh = hgrp * 4 + hl;
            {
                f32x4 acc[4];
                #pragma unroll
                for (int j = 0; j < 4; ++j) acc[j] = (f32x4)0.f;
                #pragma unroll
                for (int kt = 0; kt < 2; ++kt) {
                    bf16x8 af = *(const bf16x8*)&U.p2.Ps[hh2][w*16 + fr][kt*32 + kc*8];
                    #pragma unroll
                    for (int j = 0; j < 4; ++j) {
                        bf16x8 bfv = *(const bf16x8*)&U.p2.Xt[hh2][j*16 + fr][kt*32 + kc*8];
                        acc[j] = __builtin_amdgcn_mfma_f32_16x16x32_bf16(af, bfv, acc[j], 0, 0, 0);
                    }
                }
                #pragma unroll
                for (int j = 0; j < 4; ++j)
                    #pragma unroll
                    for (int q = 0; q < 4; ++q) {
                        int l = w*16 + (lane >> 4)*4 + q;
                        int p = j*16 + fr;
                        ybuf[(size_t)(row0 + l) * DINNER + hh * HEADDIM + p] = f2bf(acc[j][q]);
                    }
            }
            {
                f32x4 acc2[4][2];
                #pragma unroll
                for (int mt = 0; mt < 4; ++mt)
                    #pragma unroll
                    for (int jt = 0; jt < 2; ++jt) acc2[mt][jt] = (f32x4)0.f;
                #pragma unroll
                for (int kt = 0; kt < 2; ++kt) {
                    bf16x8 a4[4], b2[2];
                    #pragma unroll
                    for (int mt = 0; mt < 4; ++mt) a4[mt] = *(const bf16x8*)&U.p2.Xdt[hh2][mt*16 + fr][kt*32 + kc*8];
                    #pragma unroll
                    for (int jt = 0; jt < 2; ++jt) b2[jt] = *(const bf16x8*)&Btr[w*32 + jt*16 + fr][kt*32 + kc*8];
                    #pragma unroll
                    for (int mt = 0; mt < 4; ++mt)
                        #pragma unroll
                        for (int jt = 0; jt < 2; ++jt)
                            acc2[mt][jt] = __builtin_amdgcn_mfma_f32_16x16x32_bf16(a4[mt], b2[jt], acc2[mt][jt], 0, 0, 0);
                }
                ushort* sb = states + ((((size_t)b * NCHUNK + c) * NHEADS + hh) * HEADDIM) * DSTATE;
                #pragma unroll
                for (int mt = 0; mt < 4; ++mt)
                    #pragma unroll
                    for (int jt = 0; jt < 2; ++jt)
                        #pragma unroll
                        for (int q = 0; q < 4; ++q) {
                            int p = mt*16 + (lane >> 4)*4 + q;
                            int n = w*32 + jt*16 + fr;
                            sb[(size_t)p * DSTATE + n] = f2bf(acc2[mt][jt][q]);
                        }
            }
        }
        __syncthreads();
    }
}

// ------------------------------------- inter-chunk scan (bf16 states, f32 regs)
__global__ __launch_bounds__(256) void scan_k(ushort* __restrict__ states,
                                              const float* __restrict__ chunksum) {
    const int bid = blockIdx.x;
    const int pq = bid & 3, h = (bid >> 2) & 7, b = bid >> 5;
    const int tid = threadIdx.x;
    float pref[8];
    #pragma unroll
    for (int k = 0; k < 8; ++k) pref[k] = 0.f;
    for (int c = 0; c < NCHUNK; ++c) {
        ushort* base = states + (((size_t)b * NCHUNK + c) * NHEADS + h) * (HEADDIM * DSTATE)
                       + pq * 2048 + tid * 8;
        float dec = __expf(chunksum[((size_t)b * NCHUNK + c) * NHEADS + h]);
        uint4 v = *(const uint4*)base;
        const ushort* pv = (const ushort*)&v;
        ushort outv[8];
        #pragma unroll
        for (int j = 0; j < 8; ++j) {
            float cur = bf2f(pv[j]);
            outv[j] = f2bf(pref[j]);
            pref[j] = dec * pref[j] + cur;
        }
        *(uint4*)base = *(uint4*)outv;
    }
}

// ----- Y_off + gate + RMSNorm + fused out-proj (32-row blocks, XCD-chunked)
// Heads processed in PAIRS: double Ssh buffer, 8 barrier phases instead of 16.
__global__ __launch_bounds__(256) void yoff_gate_k(const ushort* __restrict__ xbc,
                                                   const ushort* __restrict__ states,
                                                   const float* __restrict__ acsbuf,
                                                   const ushort* __restrict__ ybuf,
                                                   const ushort* __restrict__ zx,
                                                   const float* __restrict__ nw,
                                                   const ushort* __restrict__ WtB,
                                                   float* __restrict__ out) {
    const int wk = (blockIdx.x & 7) * 64 + (blockIdx.x >> 3);
    const int half = wk & 1, c = (wk >> 1) & 15, b = wk >> 5;
    const int row0 = b * SEQ + c * LCHUNK + half * 32;
    const int tid = threadIdx.x;
    const int lane = tid & 63, w = tid >> 6;
    const int fr = lane & 15, kc = lane >> 4;
    const int rw = (w & 1) * 16;           // wave row range (16 of 32)
    const int j0 = (w >> 1) * 2;           // wave col-frag pair
    __shared__ ushort Csh[32][SLDA];
    __shared__ ushort Ssh[2][64][SLDA];
    __shared__ ushort Ys[32][520];
    __shared__ float eah[2][32];

    #pragma unroll
    for (int it = 0; it < 2; ++it) {
        int idx = tid + it * 256;          // 512 grains: l(32) x ng(16)
        int l = idx >> 4, ng = idx & 15;
        *(uint4*)&Csh[l][ng * 8] =
            *(const uint4*)&xbc[(size_t)(row0 + l) * CONVDIM + DINNER + DSTATE + ng * 8];
    }
    for (int hp = 0; hp < 4; ++hp) {       // head pairs 2hp, 2hp+1
        __syncthreads();                   // prev pair's MFMAs done (covers Csh on hp=0)
        #pragma unroll
        for (int hh2 = 0; hh2 < 2; ++hh2) {
            const int hl = hp * 2 + hh2;
            const ushort* sb = states + ((((size_t)b * NCHUNK + c) * NHEADS + hl) * HEADDIM) * DSTATE;
            #pragma unroll
            for (int it = 0; it < 4; ++it) {
                int idx = tid + it * 256;
                int p = idx >> 4, ng = idx & 15;
                *(uint4*)&Ssh[hh2][p][ng * 8] = *(const uint4*)&sb[(size_t)p * DSTATE + ng * 8];
            }
        }
        if (tid < 64) {
            int hh2 = tid >> 5, t = tid & 31;
            eah[hh2][t] = __expf(acsbuf[(((size_t)b * NCHUNK + c) * NHEADS + hp*2 + hh2) * LCHUNK
                                        + half * 32 + t]);
        }
        __syncthreads();
        #pragma unroll
        for (int hh2 = 0; hh2 < 2; ++hh2) {
            const int hl = hp * 2 + hh2;
            f32x4 acc[2];
            acc[0] = (f32x4)0.f; acc[1] = (f32x4)0.f;
            #pragma unroll
            for (int kt = 0; kt < 4; ++kt) {
                bf16x8 af = *(const bf16x8*)&Csh[rw + fr][kt*32 + kc*8];
                #pragma unroll
                for (int jj = 0; jj < 2; ++jj) {
                    bf16x8 bfv = *(const bf16x8*)&Ssh[hh2][(j0+jj)*16 + fr][kt*32 + kc*8];
                    acc[jj] = __builtin_amdgcn_mfma_f32_16x16x32_bf16(af, bfv, acc[jj], 0, 0, 0);
                }
            }
            #pragma unroll
            for (int jj = 0; jj < 2; ++jj)
                #pragma unroll
                for (int q = 0; q < 4; ++q) {
                    int l = rw + (lane >> 4)*4 + q;
                    int p = (j0+jj)*16 + fr;
                    float val = bf2f(ybuf[(size_t)(row0 + l) * DINNER + hl * HEADDIM + p])
                                + acc[jj][q] * eah[hh2][l];
                    Ys[l][hl * HEADDIM + p] = f2bf(val);
                }
        }
    }
    __syncthreads();
    // gate + RMSNorm: wave w -> rows w*8 .. w*8+7; write g back into Ys (bf16)
    float nwv[8];
    #pragma unroll
    for (int j = 0; j < 8; ++j) nwv[j] = nw[lane * 8 + j];
    #pragma unroll
    for (int i = 0; i < 8; ++i) {
        int l = w * 8 + i;
        int row = row0 + l;
        uint4 zv = *(const uint4*)&zx[(size_t)row * ZXLD + lane * 8];
        const ushort* pz = (const ushort*)&zv;
        float g[8], ss = 0.f;
        #pragma unroll
        for (int j = 0; j < 8; ++j) {
            float y = bf2f(Ys[l][lane * 8 + j]);
            float z = bf2f(pz[j]);
            float sz = z / (1.f + __expf(-z));
            g[j] = y * sz;
            ss += g[j] * g[j];
        }
        #pragma unroll
        for (int off = 32; off; off >>= 1) ss += __shfl_xor(ss, off);
        float r = rsqrtf(ss / (float)DINNER + EPSV);
        ushort res[8];
        #pragma unroll
        for (int j = 0; j < 8; ++j) res[j] = f2bf(g[j] * r * nwv[j]);
        *(ushort4*)&Ys[l][lane * 8]     = *(ushort4*)&res[0];
        *(ushort4*)&Ys[l][lane * 8 + 4] = *(ushort4*)&res[4];
    }
    __syncthreads();
    // fused out-proj: out[32 x 256] = g(Ys, 32x512) @ WtB^T (WtB: [256 n][512 k])
    {
        const int cj0 = w * 4;
        f32x4 accO[2][4];
        #pragma unroll
        for (int ri = 0; ri < 2; ++ri)
            #pragma unroll
            for (int j = 0; j < 4; ++j) accO[ri][j] = (f32x4)0.f;
        for (int kt = 0; kt < 16; ++kt) {
            bf16x8 af[2], bfv[4];
            #pragma unroll
            for (int ri = 0; ri < 2; ++ri)
                af[ri] = *(const bf16x8*)&Ys[ri*16 + fr][kt*32 + kc*8];
            #pragma unroll
            for (int j = 0; j < 4; ++j) {
                int n = (cj0 + j) * 16 + fr;
                bfv[j] = *(const bf16x8*)&WtB[(size_t)n * DINNER + kt*32 + kc*8];
            }
            #pragma unroll
            for (int ri = 0; ri < 2; ++ri)
                #pragma unroll
                for (int j = 0; j < 4; ++j)
                    accO[ri][j] = __builtin_amdgcn_mfma_f32_16x16x32_bf16(af[ri], bfv[j], accO[ri][j], 0, 0, 0);
        }
        #pragma unroll
        for (int ri = 0; ri < 2; ++ri)
            #pragma unroll
            for (int j = 0; j < 4; ++j)
                #pragma unroll
                for (int q = 0; q < 4; ++q) {
                    int rr = row0 + ri*16 + (lane >> 4)*4 + q;
                    int cc = (cj0 + j)*16 + fr;
                    out[(size_t)rr * DMODEL + cc] = accO[ri][j][q];
                }
    }
}

// ---------------------------------------------------------------- launch
extern "C" void kernel_launch(void* const* d_in, const int* in_sizes, int n_in,
                              void* d_out, int out_size, void* d_ws, size_t ws_size,
                              hipStream_t stream) {
    const float* u       = (const float*)d_in[0];
    const float* W_in    = (const float*)d_in[1];
    const float* conv_w  = (const float*)d_in[2];
    const float* conv_b  = (const float*)d_in[3];
    const float* dt_bias = (const float*)d_in[4];
    const float* A_log   = (const float*)d_in[5];
    const float* Dp      = (const float*)d_in[6];
    const float* norm_w  = (const float*)d_in[7];
    const float* W_out   = (const float*)d_in[8];
    float* out = (float*)d_out;

    char* p = (char*)d_ws;
    ushort* zx       = (ushort*)p; p += (size_t)ROWS * ZXLD * sizeof(ushort);
    ushort* ybuf     = (ushort*)p; p += (size_t)ROWS * DINNER * sizeof(ushort);
    ushort* states   = (ushort*)p; p += (size_t)BATCHN * NCHUNK * NHEADS * HEADDIM * DSTATE * sizeof(ushort);
    ushort* xbc      = (ushort*)p; p += (size_t)ROWS * CONVDIM * sizeof(ushort);
    ushort* ubf      = (ushort*)p; p += (size_t)ROWS * DMODEL * sizeof(ushort);
    float*  dtb      = (float*)p;  p += (size_t)ROWS * NHEADS  * sizeof(float);
    float*  adtb     = (float*)p;  p += (size_t)ROWS * NHEADS  * sizeof(float);
    float*  chunksum = (float*)p;  p += (size_t)BATCHN * NCHUNK * NHEADS * sizeof(float);
    float*  acsbuf   = (float*)p;  p += (size_t)BATCHN * NCHUNK * NHEADS * LCHUNK * sizeof(float);
    ushort* WtA      = (ushort*)p; p += (size_t)ZXLD * DMODEL * sizeof(ushort);
    ushort* WtB      = (ushort*)p; p += (size_t)DMODEL * DINNER * sizeof(ushort);

    prep_k<<<960, 256, 0, stream>>>(u, W_in, W_out, dt_bias, A_log,
                                    ubf, dtb, adtb, WtA, WtB);
    gemm_bf16<<<(ZXLD/128)*(ROWS/128), 256, 0, stream>>>(
        ubf, WtA, zx, ROWS, ZXLD, DMODEL, ZXLD/128);
    conv_silu_k<<<(ROWS/4)*96/256, 256, 0, stream>>>(zx, conv_w, conv_b, xbc);
    ssd_mfma_k<<<512, 256, 0, stream>>>(
        xbc, dtb, adtb, Dp, ybuf, states, acsbuf, chunksum);
    scan_k<<<BATCHN*NHEADS*4, 256, 0, stream>>>(states, chunksum);
    yoff_gate_k<<<512, 256, 0, stream>>>(
        xbc, states, acsbuf, ybuf, zx, norm_w, WtB, out);
}